// Round 13
// baseline (356.255 us; speedup 1.0000x reference)
//
#include <hip/hip_runtime.h>

#define DEVI __device__ __forceinline__

typedef unsigned short u16;
typedef __attribute__((ext_vector_type(8))) short bf8v;   // 8 bf16 = 4 VGPR
typedef __attribute__((ext_vector_type(4))) short s4v;    // 4 bf16
typedef __attribute__((ext_vector_type(4))) float f4v;    // MFMA acc

constexpr int NB = 4, C = 128, H = 96, W = 96, HW = H * W;   // 9216
constexpr int HL = 48, WL = 48, HWL = HL * WL;               // 2304
constexpr int CODES = 1024, DIM = 128;
constexpr int ROWS = NB * HWL;                               // 9216 VQ rows
constexpr int PD = 40;                                       // padded LDS row stride (u16): 80B

DEVI float lrelu_f(float v) { return v >= 0.f ? v : 0.2f * v; }

DEVI u16 f2bf(float f) {  // RNE float->bf16
  union { float f; unsigned u; } v; v.f = f;
  unsigned r = (v.u + 0x7FFFu + ((v.u >> 16) & 1u)) >> 16;
  return (u16)r;
}

DEVI float bf2f(u16 h) {
  union { unsigned u; float f; } v; v.u = (unsigned)h << 16;
  return v.f;
}

DEVI void wave_red2(float& s, float& s2) {
#pragma unroll
  for (int o = 32; o > 0; o >>= 1) { s += __shfl_down(s, o); s2 += __shfl_down(s2, o); }
}

DEVI bool block_red2(float& s, float& s2) {
  wave_red2(s, s2);
  __shared__ float ls[8], ls2[8];
  int wv = threadIdx.x >> 6, ln = threadIdx.x & 63;
  if (ln == 0) { ls[wv] = s; ls2[wv] = s2; }
  __syncthreads();
  if (threadIdx.x == 0) {
    s = ls[0] + ls[1] + ls[2] + ls[3];
    s2 = ls2[0] + ls2[1] + ls2[2] + ls2[3];
    return true;
  }
  return false;
}

// insert (e,j) into ascending top-3, lexicographic (d, idx)
DEVI void ins3(float e, int j, float& d0, int& i0, float& d1, int& i1, float& d2, int& i2) {
  bool b0 = (e < d0) || (e == d0 && j < i0);
  bool b1 = (e < d1) || (e == d1 && j < i1);
  bool b2 = (e < d2) || (e == d2 && j < i2);
  float nd0 = b0 ? e : d0;             int ni0 = b0 ? j : i0;
  float nd1 = b0 ? d0 : (b1 ? e : d1); int ni1 = b0 ? i0 : (b1 ? j : i1);
  float nd2 = b1 ? d1 : (b2 ? e : d2); int ni2 = b1 ? i1 : (b2 ? j : i2);
  d0 = nd0; i0 = ni0; d1 = nd1; i1 = ni1; d2 = nd2; i2 = ni2;
}

// ---------------- stats reduction: 8 slots, PER partials each ----------------
__global__ __launch_bounds__(256) void k_red16(const float2* __restrict__ src,
                                               float* __restrict__ dst, int per) {
  int slot = blockIdx.x;
  float s = 0.f, s2 = 0.f;
  for (int i = threadIdx.x; i < per; i += 256) {
    float2 v = src[(size_t)slot * per + i];
    s += v.x; s2 += v.y;
  }
  if (block_red2(s, s2)) { dst[slot * 2] = s; dst[slot * 2 + 1] = s2; }
}

// ---------------- unified pre-pack ----------------
__global__ __launch_bounds__(256) void k_pack_all(
    const float* __restrict__ d1_w, const float* __restrict__ d0_w,
    const float* __restrict__ pj_w, const float* __restrict__ emb,
    const float* __restrict__ e1_w,
    u16* __restrict__ A1, u16* __restrict__ A0, u16* __restrict__ Apj,
    u16* __restrict__ ehtil, u16* __restrict__ We1,
    float* __restrict__ enorm, float* __restrict__ counts) {
  int b = blockIdx.x, t = threadIdx.x;
  if (b < 1152) {                                  // d1: A1[ky][ch8][kx][co128][ci32]
    int i = b * 256 + t;
    int ci = i & 31, co = (i >> 5) & 127, r = i >> 12;
    int kx = r % 3; int r2 = r / 3; int ch = r2 & 7, ky = r2 >> 3;
    A1[i] = f2bf(d1_w[((size_t)(co * 256 + ch * 32 + ci) * 3 + ky) * 3 + kx]);
  } else if (b < 1728) {                           // d0: A0[wy][ch4][wx][co128][ci32]
    int i = (b - 1152) * 256 + t;
    int ci = i & 31, co = (i >> 5) & 127, r = i >> 12;
    int wx = r % 3; int r2 = r / 3; int ch = r2 & 3, wy = r2 >> 2;
    A0[i] = f2bf(d0_w[((size_t)((ch * 32 + ci) * 128 + co) * 3 + wy) * 3 + wx]);
  } else if (b < 1792) {                           // pj: Apj[ch4][co128][ci32]
    int i = (b - 1728) * 256 + t;
    int ci = i & 31, co = (i >> 5) & 127, ch = i >> 12;
    Apj[i] = f2bf(pj_w[co * 128 + ch * 32 + ci]);
  } else if (b < 1920) {                           // emb tile-major split pack
    int g = (b - 1792) * 256 + t;
    int ct = g >> 9; int rem = g & 511;
    int j = rem >> 6; int l = rem & 63;
    int code = ct * 16 + (l & 15);
    int kb = j * 32 + (l >> 4) * 8;
    bool lo = kb >= 128; int k0 = lo ? kb - 128 : kb;
    const float* ep = emb + (size_t)code * DIM + k0;
    u16 o[8];
#pragma unroll
    for (int e = 0; e < 8; ++e) {
      float v = ep[e];
      u16 h = f2bf(v);
      o[e] = lo ? f2bf(v - bf2f(h)) : h;
    }
    bf8v ov = {(short)o[0], (short)o[1], (short)o[2], (short)o[3],
               (short)o[4], (short)o[5], (short)o[6], (short)o[7]};
    *(bf8v*)&ehtil[(size_t)g * 8] = ov;
  } else if (b < 1924) {                           // emb row norms (4 blocks)
    int e = (b - 1920) * 256 + t;
    const float4* p = (const float4*)(emb + (size_t)e * DIM);
    float s = 0.f;
#pragma unroll 8
    for (int i = 0; i < 32; ++i) {
      float4 v = p[i];
      s = fmaf(v.x, v.x, s); s = fmaf(v.y, v.y, s); s = fmaf(v.z, v.z, s); s = fmaf(v.w, v.w, s);
    }
    enorm[e] = s;
  } else if (b == 1924) {                          // zero counts (1 block)
#pragma unroll
    for (int k = 0; k < 4; ++k) counts[t + k * 256] = 0.f;
  } else {                                         // e1 weights: 36864 pair-granules
    int p = (b - 1925) * 256 + t;
    int s = p >> 6, l = p & 63;
    int ct = s & 7; int r = s >> 3;
    int kx = r % 3; int r2 = r / 3; int ch = r2 & 3, ky = r2 >> 2;
    int co = ct * 16 + (l & 15), ci0 = ch * 32 + (l >> 4) * 8;
    u16 hh[8], ll[8];
#pragma unroll
    for (int e = 0; e < 8; ++e) {
      float v = e1_w[((size_t)(co * 128 + ci0 + e) * 3 + ky) * 3 + kx];
      u16 h = f2bf(v); hh[e] = h; ll[e] = f2bf(v - bf2f(h));
    }
    bf8v hv = {(short)hh[0], (short)hh[1], (short)hh[2], (short)hh[3],
               (short)hh[4], (short)hh[5], (short)hh[6], (short)hh[7]};
    bf8v lv = {(short)ll[0], (short)ll[1], (short)ll[2], (short)ll[3],
               (short)ll[4], (short)ll[5], (short)ll[6], (short)ll[7]};
    *(bf8v*)&We1[(size_t)s * 1024 + l * 8] = hv;
    *(bf8v*)&We1[(size_t)s * 1024 + 512 + l * 8] = lv;
  }
}

// ---------------- conv e0 tiled: 3x3, Cin=4, s=1, p=1 ----------------
__global__ __launch_bounds__(256) void k_conv_e0t(
    const float* __restrict__ x, const float* __restrict__ wg,
    const float* __restrict__ bias, float* __restrict__ out, float2* __restrict__ ps) {
  __shared__ float xs[4][18][104];
  int b = blockIdx.x;
  int rq = b % 6; int co = (b / 6) & 127; int n = b / 768;
  int t = threadIdx.x;
  int tx = t & 15, r = t >> 4;
  int y0 = rq * 16;
  for (int e = t; e < 4 * 18 * 104; e += 256) {
    int ci = e / 1872; int rem = e - ci * 1872;
    int row = rem / 104; int off = rem - row * 104;
    int iy = y0 - 1 + row; int ix = off - 1;
    float v = 0.f;
    if ((unsigned)iy < 96u && (unsigned)ix < 96u)
      v = x[((size_t)(n * 4 + ci)) * HW + iy * 96 + ix];
    xs[ci][row][off] = v;
  }
  float wr[4][9];
  const float* wp = wg + co * 36;
#pragma unroll
  for (int ci = 0; ci < 4; ++ci)
#pragma unroll
    for (int k = 0; k < 9; ++k) wr[ci][k] = wp[ci * 9 + k];
  float bv = bias[co];
  __syncthreads();
  float acc[6];
#pragma unroll
  for (int p = 0; p < 6; ++p) acc[p] = bv;
#pragma unroll
  for (int ci = 0; ci < 4; ++ci) {
#pragma unroll
    for (int ky = 0; ky < 3; ++ky) {
      const float* rp = &xs[ci][r + ky][6 * tx];
      float f[8];
#pragma unroll
      for (int j = 0; j < 4; ++j) {
        float2 v2 = *(const float2*)(rp + 2 * j);
        f[2 * j] = v2.x; f[2 * j + 1] = v2.y;
      }
      float w0 = wr[ci][ky * 3 + 0], w1 = wr[ci][ky * 3 + 1], w2 = wr[ci][ky * 3 + 2];
#pragma unroll
      for (int p = 0; p < 6; ++p)
        acc[p] = fmaf(w0, f[p], fmaf(w1, f[p + 1], fmaf(w2, f[p + 2], acc[p])));
    }
  }
  float* op = out + ((size_t)(n * 128 + co) * 96 + (y0 + r)) * 96 + 6 * tx;
#pragma unroll
  for (int j = 0; j < 3; ++j) {
    float2 v2 = { acc[2 * j], acc[2 * j + 1] };
    *(float2*)(op + 2 * j) = v2;
  }
  float s = 0.f, s2 = 0.f;
#pragma unroll
  for (int p = 0; p < 6; ++p) { s += acc[p]; s2 += acc[p] * acc[p]; }
  if (block_red2(s, s2)) {
    int slot = n * 2 + (co >> 6);
    ps[(size_t)slot * 384 + (co & 63) * 6 + rq] = make_float2(s, s2);
  }
}

// ---------------- GN(e0)+lrelu -> parity-split hi/lo bf16 pack for e1 MFMA ----------------
__global__ __launch_bounds__(256) void k_gn_px(
    const float* __restrict__ enc1, const float* __restrict__ stats,
    const float* __restrict__ gam, const float* __restrict__ bet, u16* __restrict__ xp) {
  int b = blockIdx.x;
  int ch = b & 3; int iy = (b >> 2) % 96; int n = b / 384;
  int t = threadIdx.x;
  const float invc = 1.f / (64.f * 9216.f);
  size_t chunk = ((size_t)((n * 96 + iy) * 4 + ch)) * 6208;
  for (int e = t; e < 388; e += 256) {
    int oct = e / 97, u = e - oct * 97;
    int ix = (u < 48) ? 2 * u : 2 * (u - 48) - 1;
    u16* dh = xp + chunk + u * 32 + oct * 8;
    u16* dl = dh + 3104;
    if (ix < 0) {
      bf8v z = {0, 0, 0, 0, 0, 0, 0, 0};
      *(bf8v*)dh = z; *(bf8v*)dl = z;
      continue;
    }
    u16 hh[8], ll[8];
#pragma unroll
    for (int e8 = 0; e8 < 8; ++e8) {
      int c = ch * 32 + oct * 8 + e8;
      const float* st = stats + (n * 2 + (c >> 6)) * 2;
      float mu = st[0] * invc;
      float var = fmaf(-mu, mu, st[1] * invc);
      float rs = rsqrtf(var + 1e-5f);
      float raw = enc1[((size_t)(n * 128 + c)) * 9216 + iy * 96 + ix];
      float v = lrelu_f(fmaf((raw - mu) * rs, gam[c], bet[c]));
      u16 h = f2bf(v); hh[e8] = h; ll[e8] = f2bf(v - bf2f(h));
    }
    bf8v hv = {(short)hh[0], (short)hh[1], (short)hh[2], (short)hh[3],
               (short)hh[4], (short)hh[5], (short)hh[6], (short)hh[7]};
    bf8v lv = {(short)ll[0], (short)ll[1], (short)ll[2], (short)ll[3],
               (short)ll[4], (short)ll[5], (short)ll[6], (short)ll[7]};
    *(bf8v*)dh = hv; *(bf8v*)dl = lv;
  }
}

// ---------------- e1 conv via split-bf16 MFMA: NO LDS / NO barriers, XCD swizzle ----------------
__global__ __launch_bounds__(256) void k_conv_e1m(
    const u16* __restrict__ xp, const u16* __restrict__ We1,
    const float* __restrict__ bias, float* __restrict__ latent, float2* __restrict__ ps) {
  __shared__ float ls[4], ls2[4];
  int braw = blockIdx.x;
  int b = (braw & 7) * 48 + (braw >> 3);         // 384 = 8 XCD x 48
  int cb = b & 1; int oy = (b >> 1) % 48; int n = b / 96;
  int t = threadIdx.x; int w = t >> 6; int lane = t & 63;
  int ln16 = lane & 15, quad = lane >> 4;
  int ctg = cb * 4 + w;
  f4v acc[3];
#pragma unroll
  for (int nt = 0; nt < 3; ++nt) acc[nt] = (f4v){0.f, 0.f, 0.f, 0.f};
  for (int ky = 0; ky < 3; ++ky) {
    int iy = 2 * oy + ky - 1;
    if ((unsigned)iy >= 96u) continue;
    for (int ch = 0; ch < 4; ++ch) {
      const u16* chunk = xp + ((size_t)((n * 96 + iy) * 4 + ch)) * 6208;
      const u16* wb = We1 + ((size_t)((ky * 4 + ch) * 3)) * 8192;
      bf8v ah[3], al[3];
#pragma unroll
      for (int kx = 0; kx < 3; ++kx) {
        const u16* sl = wb + (kx * 8 + ctg) * 1024 + lane * 8;
        ah[kx] = *(const bf8v*)sl;
        al[kx] = *(const bf8v*)(sl + 512);
      }
#pragma unroll
      for (int nt = 0; nt < 3; ++nt) {
        int px = nt * 16 + ln16;
        const u16* be = chunk + px * 32 + quad * 8;
        const u16* bo = chunk + (48 + px) * 32 + quad * 8;
        bf8v bhe  = *(const bf8v*)be;
        bf8v ble  = *(const bf8v*)(be + 3104);
        bf8v bho0 = *(const bf8v*)bo;
        bf8v blo0 = *(const bf8v*)(bo + 3104);
        bf8v bho1 = *(const bf8v*)(bo + 32);
        bf8v blo1 = *(const bf8v*)(bo + 32 + 3104);
        acc[nt] = __builtin_amdgcn_mfma_f32_16x16x32_bf16(ah[1], bhe, acc[nt], 0, 0, 0);
        acc[nt] = __builtin_amdgcn_mfma_f32_16x16x32_bf16(al[1], bhe, acc[nt], 0, 0, 0);
        acc[nt] = __builtin_amdgcn_mfma_f32_16x16x32_bf16(ah[1], ble, acc[nt], 0, 0, 0);
        acc[nt] = __builtin_amdgcn_mfma_f32_16x16x32_bf16(ah[0], bho0, acc[nt], 0, 0, 0);
        acc[nt] = __builtin_amdgcn_mfma_f32_16x16x32_bf16(al[0], bho0, acc[nt], 0, 0, 0);
        acc[nt] = __builtin_amdgcn_mfma_f32_16x16x32_bf16(ah[0], blo0, acc[nt], 0, 0, 0);
        acc[nt] = __builtin_amdgcn_mfma_f32_16x16x32_bf16(ah[2], bho1, acc[nt], 0, 0, 0);
        acc[nt] = __builtin_amdgcn_mfma_f32_16x16x32_bf16(al[2], bho1, acc[nt], 0, 0, 0);
        acc[nt] = __builtin_amdgcn_mfma_f32_16x16x32_bf16(ah[2], blo1, acc[nt], 0, 0, 0);
      }
    }
  }
  int co0 = cb * 64 + w * 16 + quad * 4;
  float4 bv = *(const float4*)&bias[co0];
  float s = 0.f, s2 = 0.f;
#pragma unroll
  for (int nt = 0; nt < 3; ++nt) {
    int px = nt * 16 + ln16;
#pragma unroll
    for (int g = 0; g < 4; ++g) {
      float bvg = (g == 0) ? bv.x : (g == 1) ? bv.y : (g == 2) ? bv.z : bv.w;
      float v = acc[nt][g] + bvg;
      latent[((size_t)(n * 128 + co0 + g)) * 2304 + oy * 48 + px] = v;
      s += v; s2 += v * v;
    }
  }
  wave_red2(s, s2);
  if (lane == 0) { ls[w] = s; ls2[w] = s2; }
  __syncthreads();
  if (t == 0) {
    int slot = n * 2 + cb;
    ps[(size_t)slot * 48 + oy] =
        make_float2(ls[0] + ls[1] + ls[2] + ls[3], ls2[0] + ls2[1] + ls2[2] + ls2[3]);
  }
}

// ---------------- GN + lrelu, NHWC fp32 -> bf16 (d0 layer) ----------------
__global__ __launch_bounds__(256) void k_gn_nhwc_bf(
    const float* __restrict__ in, u16* __restrict__ outb, const float* __restrict__ stats,
    const float* __restrict__ gam, const float* __restrict__ bet) {
  int idx = blockIdx.x * 256 + threadIdx.x;
  int c = idx & 127;
  int n = idx / (9216 * 128);
  const float* st = stats + (n * 2 + (c >> 6)) * 2;
  const float invcnt = 1.f / (64.f * 9216.f);
  float mu = st[0] * invcnt;
  float var = fmaf(-mu, mu, st[1] * invcnt);
  float rs = rsqrtf(var + 1e-5f);
  float v = in[idx];
  outb[idx] = f2bf(lrelu_f(fmaf((v - mu) * rs, gam[c], bet[c])));
}

// ---------------- pv 1x1 conv fp32, fused e1-GN -> zp split bf16 ----------------
__global__ __launch_bounds__(256, 2) void k_pv(
    const float* __restrict__ in, const float* __restrict__ w,
    const float* __restrict__ bias, const float* __restrict__ stats1,
    const float* __restrict__ gam, const float* __restrict__ bet,
    u16* __restrict__ zp) {
  int b = blockIdx.x;
  int pxb = b % 36; int cb = (b / 36) & 1; int n = b / 72;
  int t = threadIdx.x;
  int pxg = t & 7, cg = t >> 3;
  int px0 = pxb * 64 + pxg * 8;
  int cobase = cb * 64 + cg * 2;
  const float invc = 1.f / (64.f * 2304.f);
  float acc[2][8];
#pragma unroll
  for (int c = 0; c < 2; ++c) {
    float bv = bias[cobase + c];
#pragma unroll
    for (int p = 0; p < 8; ++p) acc[c][p] = bv;
  }
  const float* ipb = in + (size_t)n * 128 * HWL + px0;
  for (int ci0 = 0; ci0 < 128; ci0 += 4) {
    float inr[4][8];
#pragma unroll
    for (int i = 0; i < 4; ++i) {
      int c = ci0 + i;
      const float* st = stats1 + (n * 2 + (c >> 6)) * 2;
      float mu = st[0] * invc;
      float var = fmaf(-mu, mu, st[1] * invc);
      float rsv = rsqrtf(var + 1e-5f);
      float ga = gam[c], be = bet[c];
      const float* ip = ipb + (size_t)c * HWL;
      float4 a = *(const float4*)ip; float4 bq = *(const float4*)(ip + 4);
      inr[i][0] = lrelu_f(fmaf((a.x - mu) * rsv, ga, be));
      inr[i][1] = lrelu_f(fmaf((a.y - mu) * rsv, ga, be));
      inr[i][2] = lrelu_f(fmaf((a.z - mu) * rsv, ga, be));
      inr[i][3] = lrelu_f(fmaf((a.w - mu) * rsv, ga, be));
      inr[i][4] = lrelu_f(fmaf((bq.x - mu) * rsv, ga, be));
      inr[i][5] = lrelu_f(fmaf((bq.y - mu) * rsv, ga, be));
      inr[i][6] = lrelu_f(fmaf((bq.z - mu) * rsv, ga, be));
      inr[i][7] = lrelu_f(fmaf((bq.w - mu) * rsv, ga, be));
    }
    float wr[2][4];
#pragma unroll
    for (int c = 0; c < 2; ++c) {
      float4 wv = *(const float4*)&w[(size_t)(cobase + c) * 128 + ci0];
      wr[c][0] = wv.x; wr[c][1] = wv.y; wr[c][2] = wv.z; wr[c][3] = wv.w;
    }
#pragma unroll
    for (int i = 0; i < 4; ++i)
#pragma unroll
      for (int c = 0; c < 2; ++c)
#pragma unroll
        for (int p = 0; p < 8; ++p) acc[c][p] = fmaf(wr[c][i], inr[i][p], acc[c][p]);
  }
#pragma unroll
  for (int p = 0; p < 8; ++p) {
    size_t r = (size_t)n * HWL + px0 + p;
    u16 h0 = f2bf(acc[0][p]); u16 l0 = f2bf(acc[0][p] - bf2f(h0));
    u16 h1 = f2bf(acc[1][p]); u16 l1 = f2bf(acc[1][p] - bf2f(h1));
    unsigned hp = (unsigned)h0 | ((unsigned)h1 << 16);
    unsigned lp = (unsigned)l0 | ((unsigned)l1 << 16);
    *(unsigned*)&zp[r * 256 + cobase] = hp;
    *(unsigned*)&zp[r * 256 + 128 + cobase] = lp;
  }
}

// ---------------- VQ via MFMA: 8-wave blocks, 8 tiles/wave, VGPR<=128 ----------------
__global__ __launch_bounds__(512, 4) void k_vq(
    const u16* __restrict__ zp, const u16* __restrict__ ehtil,
    const float* __restrict__ emb, const float* __restrict__ enorm,
    u16* __restrict__ qb, float* __restrict__ counts, float* __restrict__ pvq) {
  __shared__ float wd[8][16][3];
  __shared__ int   wi[8][16][3];
  __shared__ float lred[8];
  __shared__ int hist[CODES];
  int r0 = blockIdx.x * 16;
  int t = threadIdx.x, w = t >> 6, lane = t & 63;
  int ln16 = lane & 15, quad = lane >> 4;
  hist[t] = 0; hist[t + 512] = 0;
  const u16* zrow = zp + (size_t)(r0 + ln16) * 256 + quad * 8;
  bf8v bh[4], bl[4];
#pragma unroll
  for (int kk = 0; kk < 4; ++kk) {
    bh[kk] = *(const bf8v*)(zrow + kk * 32);
    bl[kk] = *(const bf8v*)(zrow + 128 + kk * 32);
  }
  float d0 = 3.4e38f, d1 = 3.4e38f, d2 = 3.4e38f;
  int i0 = -1, i1 = -1, i2 = -1;
  const u16* abase = ehtil + (size_t)(w * 8) * 4096 + lane * 8;
#pragma unroll
  for (int tt = 0; tt < 8; ++tt) {
    const u16* ap = abase + tt * 4096;
    bf8v af[8];
#pragma unroll
    for (int j = 0; j < 8; ++j) af[j] = *(const bf8v*)(ap + j * 512);
    f4v accA = (f4v){0.f, 0.f, 0.f, 0.f};
    f4v accB = (f4v){0.f, 0.f, 0.f, 0.f};
    f4v accC = (f4v){0.f, 0.f, 0.f, 0.f};
#pragma unroll
    for (int kk = 0; kk < 4; ++kk) {
      accA = __builtin_amdgcn_mfma_f32_16x16x32_bf16(af[kk], bh[kk], accA, 0, 0, 0);
      accB = __builtin_amdgcn_mfma_f32_16x16x32_bf16(af[4 + kk], bh[kk], accB, 0, 0, 0);
      accC = __builtin_amdgcn_mfma_f32_16x16x32_bf16(af[kk], bl[kk], accC, 0, 0, 0);
    }
    int cbase = (w * 8 + tt) * 16 + quad * 4;
#pragma unroll
    for (int g = 0; g < 4; ++g) {
      int code = cbase + g;
      float dot = accA[g] + accB[g] + accC[g];
      float d = fmaf(-2.f, dot, enorm[code]);
      bool b0 = d < d0, b1 = d < d1, b2 = d < d2;
      float nd0 = b0 ? d : d0;             int ni0 = b0 ? code : i0;
      float nd1 = b0 ? d0 : (b1 ? d : d1); int ni1 = b0 ? i0 : (b1 ? code : i1);
      float nd2 = b1 ? d1 : (b2 ? d : d2); int ni2 = b1 ? i1 : (b2 ? code : i2);
      d0 = nd0; i0 = ni0; d1 = nd1; i1 = ni1; d2 = nd2; i2 = ni2;
    }
  }
#pragma unroll
  for (int off = 16; off <= 32; off <<= 1) {
    float e0 = __shfl_xor(d0, off), e1 = __shfl_xor(d1, off), e2 = __shfl_xor(d2, off);
    int j0 = __shfl_xor(i0, off), j1 = __shfl_xor(i1, off), j2 = __shfl_xor(i2, off);
    ins3(e0, j0, d0, i0, d1, i1, d2, i2);
    ins3(e1, j1, d0, i0, d1, i1, d2, i2);
    ins3(e2, j2, d0, i0, d1, i1, d2, i2);
  }
  if (quad == 0) {
    wd[w][ln16][0] = d0; wd[w][ln16][1] = d1; wd[w][ln16][2] = d2;
    wi[w][ln16][0] = i0; wi[w][ln16][1] = i1; wi[w][ln16][2] = i2;
  }
  __syncthreads();
  float lsum = 0.f;
  for (int ii = 0; ii < 2; ++ii) {
    int i = w * 2 + ii;
    float bd; int bi;
    if (lane < 24) { bd = wd[lane / 3][i][lane % 3]; bi = wi[lane / 3][i][lane % 3]; }
    else { bd = 3.4e38f; bi = 0x7fffffff; }
    int a[3];
#pragma unroll
    for (int p = 0; p < 3; ++p) {
      float d = bd; int idx = bi;
#pragma unroll
      for (int o = 1; o <= 32; o <<= 1) {
        float od = __shfl_xor(d, o); int oi = __shfl_xor(idx, o);
        if (od < d || (od == d && oi < idx)) { d = od; idx = oi; }
      }
      a[p] = idx;
      if (bi == idx) { bd = 3.4e38f; bi = 0x7fffffff; }
    }
    int r = r0 + i;
    const float* q0p = emb + (size_t)a[0] * DIM;
    const u16* zr = zp + (size_t)r * 256;
    float lp = 0.f;
#pragma unroll
    for (int cc = 0; cc < 2; ++cc) {
      int c = lane + cc * 64;
      float qv = q0p[c];
      qb[(size_t)r * 128 + c] = f2bf(qv);
      float zv = bf2f(zr[c]) + bf2f(zr[128 + c]);
      float dd = zv - qv;
      lp = fmaf(dd, dd, lp);
    }
#pragma unroll
    for (int o = 32; o > 0; o >>= 1) lp += __shfl_down(lp, o);
    if (lane == 0) { lsum += lp; atomicAdd(&hist[a[2]], 1); }
  }
  if (lane == 0) lred[w] = lsum;
  __syncthreads();
  if (t == 0) {
    float s = 0.f;
#pragma unroll
    for (int q = 0; q < 8; ++q) s += lred[q];
    pvq[blockIdx.x] = s;
  }
#pragma unroll
  for (int k = 0; k < 2; ++k) {
    int e = t + k * 512;
    int cnt = hist[e];
    if (cnt) atomicAdd(&counts[e], (float)cnt);
  }
}

// ---------------- finalize ----------------
__global__ __launch_bounds__(256) void k_finalize(
    const float* __restrict__ counts, const float* __restrict__ pvq, float* __restrict__ out) {
  float local = 0.f;
#pragma unroll
  for (int k = 0; k < 4; ++k) {
    float cnt = counts[threadIdx.x + k * 256];
    float pr = cnt * (1.f / (float)ROWS);
    local = fmaf(pr, logf(pr + 1e-10f), local);
  }
  float lsum = 0.f;
  for (int i = threadIdx.x; i < ROWS / 16; i += 256) lsum += pvq[i];
  if (block_red2(local, lsum)) {
    out[1 + NB * 4 * HW] = expf(-local);
    out[0] = 0.25f * lsum * (1.f / (9216.f * 128.f));
  }
}

// ---------------- proj (1x1) MFMA, fused e0-GN; padded LDS ----------------
__global__ __launch_bounds__(256) void k_proj_m(
    const float* __restrict__ enc1, const u16* __restrict__ Apj,
    const float* __restrict__ bias, const float* __restrict__ stats0,
    const float* __restrict__ gam, const float* __restrict__ bet,
    u16* __restrict__ skipb) {
  __shared__ u16 Ash[128 * PD];
  __shared__ u16 Bsh[96 * PD];
  int b = blockIdx.x; int rowi = b % 96; int n = b / 96; int px0 = rowi * 96;
  int t = threadIdx.x; int w = t >> 6; int lane = t & 63;
  int ln16 = lane & 15, quad = lane >> 4;
  int co0w = (w & 1) * 64; int pxh = (w >> 1) * 48;
  int c_l = t & 31, xg = t >> 5;
  const float invc = 1.f / (64.f * 9216.f);
  f4v acc[4][3];
#pragma unroll
  for (int mt = 0; mt < 4; ++mt)
#pragma unroll
    for (int nt = 0; nt < 3; ++nt) acc[mt][nt] = (f4v){0.f, 0.f, 0.f, 0.f};
  for (int ch = 0; ch < 4; ++ch) {
    __syncthreads();
#pragma unroll
    for (int e = 0; e < 2; ++e) {
      int i = t + e * 256;
      *(bf8v*)&Ash[(i >> 2) * PD + (i & 3) * 8] = *(const bf8v*)&Apj[ch * 4096 + i * 8];
    }
    int c = ch * 32 + c_l;
    const float* st = stats0 + (n * 2 + (ch >> 1)) * 2;
    float mu = st[0] * invc;
    float var = fmaf(-mu, mu, st[1] * invc);
    float rsv = rsqrtf(var + 1e-5f);
    float ga = gam[c], be = bet[c];
    const float* ip = enc1 + (size_t)(n * 128 + c) * 9216 + px0 + xg * 12;
#pragma unroll
    for (int j4 = 0; j4 < 3; ++j4) {
      float4 v = *(const float4*)(ip + j4 * 4);
      int pxb = xg * 12 + j4 * 4;
      Bsh[(pxb + 0) * PD + c_l] = f2bf(lrelu_f(fmaf((v.x - mu) * rsv, ga, be)));
      Bsh[(pxb + 1) * PD + c_l] = f2bf(lrelu_f(fmaf((v.y - mu) * rsv, ga, be)));
      Bsh[(pxb + 2) * PD + c_l] = f2bf(lrelu_f(fmaf((v.z - mu) * rsv, ga, be)));
      Bsh[(pxb + 3) * PD + c_l] = f2bf(lrelu_f(fmaf((v.w - mu) * rsv, ga, be)));
    }
    __syncthreads();
    bf8v af[4];
#pragma unroll
    for (int mt = 0; mt < 4; ++mt)
      af[mt] = *(const bf8v*)&Ash[(co0w + mt * 16 + ln16) * PD + quad * 8];
#pragma unroll
    for (int nt = 0; nt < 3; ++nt) {
      bf8v bfv = *(const bf8v*)&Bsh[(pxh + nt * 16 + ln16) * PD + quad * 8];
#pragma unroll
      for (int mt = 0; mt < 4; ++mt)
        acc[mt][nt] = __builtin_amdgcn_mfma_f32_16x16x32_bf16(af[mt], bfv, acc[mt][nt], 0, 0, 0);
    }
  }
#pragma unroll
  for (int mt = 0; mt < 4; ++mt) {
    int co = co0w + mt * 16 + quad * 4;
    float4 bv = *(const float4*)&bias[co];
#pragma unroll
    for (int nt = 0; nt < 3; ++nt) {
      int px = px0 + pxh + nt * 16 + ln16;
      u16* dp = skipb + (size_t)(n * 9216 + px) * 128 + co;
      s4v sv;
      sv.x = (short)f2bf(acc[mt][nt].x + bv.x);
      sv.y = (short)f2bf(acc[mt][nt].y + bv.y);
      sv.z = (short)f2bf(acc[mt][nt].z + bv.z);
      sv.w = (short)f2bf(acc[mt][nt].w + bv.w);
      *(s4v*)dp = sv;
    }
  }
}

// ---------------- d0 conv-transpose MFMA (LDS staged, XCD swizzle, padded LDS) ----------------
__global__ __launch_bounds__(256) void k_convt_d0m(
    const u16* __restrict__ qb, const u16* __restrict__ A0,
    const float* __restrict__ bias, float* __restrict__ h, float2* __restrict__ ps) {
  __shared__ u16 Ash[2 * 128 * PD];
  __shared__ u16 Bsh[49 * PD];
  int braw = blockIdx.x;
  int b = (braw & 7) * 96 + (braw >> 3);         // 768 = 8 XCD x 96, bijective
  int rx = b & 1; int oy = (b >> 1) % 96; int n = b / 192;
  int t = threadIdx.x; int w = t >> 6; int lane = t & 63;
  int ln16 = lane & 15, quad = lane >> 4;
  int co0w = w * 32;
  f4v acc[2][3];
#pragma unroll
  for (int mt = 0; mt < 2; ++mt)
#pragma unroll
    for (int nt = 0; nt < 3; ++nt) acc[mt][nt] = (f4v){0.f, 0.f, 0.f, 0.f};
  int nyt, wys[2], iys[2];
  if (oy & 1) {
    wys[0] = 2; iys[0] = (oy - 1) >> 1;
    wys[1] = 0; iys[1] = (oy + 1) >> 1;
    nyt = (iys[1] < 48) ? 2 : 1;
  } else { wys[0] = 1; iys[0] = oy >> 1; wys[1] = 0; iys[1] = 0; nyt = 1; }
  int nxt = rx ? 2 : 1;
  int wxs[2], xof[2];
  if (rx) { wxs[0] = 2; xof[0] = 0; wxs[1] = 0; xof[1] = 1; }
  else { wxs[0] = 1; xof[0] = 0; wxs[1] = 0; xof[1] = 0; }
  for (int yt = 0; yt < nyt; ++yt) {
    for (int ch = 0; ch < 4; ++ch) {
      __syncthreads();
      for (int e = t; e < nxt * 512; e += 256) {
        int xt = e >> 9, e2 = e & 511;
        const u16* Asrc = A0 + (size_t)(((wys[yt] * 4 + ch) * 3 + wxs[xt]) * 4096);
        *(bf8v*)&Ash[xt * 128 * PD + (e2 >> 2) * PD + (e2 & 3) * 8] = *(const bf8v*)&Asrc[e2 * 8];
      }
      const u16* bbase = qb + (size_t)(n * 2304 + iys[yt] * 48) * 128 + ch * 32;
      for (int e = t; e < 196; e += 256) {
        int row = e >> 2, seg = e & 3;
        bf8v v = {0, 0, 0, 0, 0, 0, 0, 0};
        if (row < 48) v = *(const bf8v*)&bbase[row * 128 + seg * 8];
        *(bf8v*)&Bsh[row * PD + seg * 8] = v;
      }
      __syncthreads();
      for (int xt = 0; xt < nxt; ++xt) {
        bf8v af[2];
#pragma unroll
        for (int mt = 0; mt < 2; ++mt)
          af[mt] = *(const bf8v*)&Ash[xt * 128 * PD + (co0w + mt * 16 + ln16) * PD + quad * 8];
#pragma unroll
        for (int nt = 0; nt < 3; ++nt) {
          bf8v bfv = *(const bf8v*)&Bsh[(nt * 16 + ln16 + xof[xt]) * PD + quad * 8];
#pragma unroll
          for (int mt = 0; mt < 2; ++mt)
            acc[mt][nt] = __builtin_amdgcn_mfma_f32_16x16x32_bf16(af[mt], bfv, acc[mt][nt], 0, 0, 0);
        }
      }
    }
  }
  float s = 0.f, s2 = 0.f;
#pragma unroll
  for (int mt = 0; mt < 2; ++mt) {
    int co = co0w + mt * 16 + quad * 4;
    float4 bv = *(const float4*)&bias[co];
#pragma unroll
    for (int nt = 0; nt < 3; ++nt) {
      int px = nt * 16 + ln16;
      int ox = 2 * px + rx;
      float4 v;
      v.x = acc[mt][nt].x + bv.x; v.y = acc[mt][nt].y + bv.y;
      v.z = acc[mt][nt].z + bv.z; v.w = acc[mt][nt].w + bv.w;
      *(float4*)(h + (size_t)(n * 9216 + oy * 96 + ox) * 128 + co) = v;
      s += v.x + v.y + v.z + v.w;
      s2 += v.x * v.x + v.y * v.y + v.z * v.z + v.w * v.w;
    }
  }
  wave_red2(s, s2);
  if (lane == 0) {
    int slot = n * 2 + (w >> 1);
    ps[(size_t)slot * 384 + (oy * 2 + rx) * 2 + (w & 1)] = make_float2(s, s2);
  }
}

// ---------------- d1 conv MFMA: merged-cb block (128co x 96px), 4 waves x (64co x 48px) ----------------
// grid NB*96 = 384 (8 XCD x 48 swizzle); per wave mt=4, nt=3 -> 21 ds_reads : 36 MFMA per stage.
__global__ __launch_bounds__(256) void k_conv_d1m(
    const u16* __restrict__ hb, const u16* __restrict__ sb,
    const u16* __restrict__ A1, const float* __restrict__ bias,
    float* __restrict__ y, float2* __restrict__ ps) {
  __shared__ u16 Ash[3 * 128 * PD];  // [kx][co128][PD] 30.7 KB
  __shared__ u16 Bsh[98 * PD];       // 7.8 KB
  int braw = blockIdx.x;
  int b = (braw & 7) * 48 + (braw >> 3);         // 384 = 8 XCD x 48, bijective
  int oy = b % 96; int n = b / 96;
  int t = threadIdx.x; int w = t >> 6; int lane = t & 63;
  int ln16 = lane & 15, quad = lane >> 4;
  int co0w = (w & 1) * 64; int pxh = (w >> 1) * 48;
  f4v acc[4][3];
#pragma unroll
  for (int mt = 0; mt < 4; ++mt)
#pragma unroll
    for (int nt = 0; nt < 3; ++nt) acc[mt][nt] = (f4v){0.f, 0.f, 0.f, 0.f};
  int ky0 = (oy == 0) ? 1 : 0, ky1 = (oy == 95) ? 1 : 2;
  for (int ky = ky0; ky <= ky1; ++ky) {
    int iy = oy + ky - 1;
    for (int ch = 0; ch < 8; ++ch) {
      const u16* src = (ch < 4) ? hb : sb;
      int c0 = (ch & 3) * 32;
      const u16* Asrc = A1 + (size_t)(ky * 8 + ch) * 12288;   // [kx][co128][ci32]
      const u16* bbase = src + (size_t)(n * 9216 + iy * 96) * 128 + c0;
      __syncthreads();
#pragma unroll
      for (int j = 0; j < 6; ++j) {                 // 1536 granules: full 128-co A
        int e = t + j * 256;
        int kx = e >> 9; int e2 = e & 511; int co_l = e2 >> 2; int seg = e2 & 3;
        *(bf8v*)&Ash[(kx * 128 + co_l) * PD + seg * 8] =
            *(const bf8v*)&Asrc[(size_t)kx * 4096 + co_l * 32 + seg * 8];
      }
      for (int e = t; e < 392; e += 256) {
        int row = e >> 2, seg = e & 3;
        int ix = row - 1;
        bf8v v = {0, 0, 0, 0, 0, 0, 0, 0};
        if ((unsigned)ix < 96u) v = *(const bf8v*)&bbase[ix * 128 + seg * 8];
        *(bf8v*)&Bsh[row * PD + seg * 8] = v;
      }
      __syncthreads();
#pragma unroll
      for (int kx = 0; kx < 3; ++kx) {
        bf8v af[4];
#pragma unroll
        for (int mt = 0; mt < 4; ++mt)
          af[mt] = *(const bf8v*)&Ash[(kx * 128 + co0w + mt * 16 + ln16) * PD + quad * 8];
#pragma unroll
        for (int nt = 0; nt < 3; ++nt) {
          bf8v bfv = *(const bf8v*)&Bsh[(pxh + nt * 16 + ln16 + kx) * PD + quad * 8];
#pragma unroll
          for (int mt = 0; mt < 4; ++mt)
            acc[mt][nt] = __builtin_amdgcn_mfma_f32_16x16x32_bf16(af[mt], bfv, acc[mt][nt], 0, 0, 0);
        }
      }
    }
  }
  float s = 0.f, s2 = 0.f;
#pragma unroll
  for (int mt = 0; mt < 4; ++mt) {
    int co = co0w + mt * 16 + quad * 4;
    float4 bv = *(const float4*)&bias[co];
#pragma unroll
    for (int nt = 0; nt < 3; ++nt) {
      int px = pxh + nt * 16 + ln16;
      float4 v;
      v.x = acc[mt][nt].x + bv.x; v.y = acc[mt][nt].y + bv.y;
      v.z = acc[mt][nt].z + bv.z; v.w = acc[mt][nt].w + bv.w;
      *(float4*)(y + (size_t)(n * 9216 + oy * 96 + px) * 128 + co) = v;
      s += v.x + v.y + v.z + v.w;
      s2 += v.x * v.x + v.y * v.y + v.z * v.z + v.w * v.w;
    }
  }
  wave_red2(s, s2);
  if (lane == 0) {
    int slot = n * 2 + (w & 1);                    // co-half = GN group
    ps[(size_t)slot * 192 + oy * 2 + (w >> 1)] = make_float2(s, s2);
  }
}

// ---------------- readout, fused d1-GN ----------------
__global__ __launch_bounds__(256) void k_ro(
    const float* __restrict__ y, const float* __restrict__ w,
    const float* __restrict__ bias, const float* __restrict__ stats3,
    const float* __restrict__ gam, const float* __restrict__ bet,
    float* __restrict__ out) {
  __shared__ float wsh[512];
  __shared__ float gsh[128], bsh[128];
  __shared__ float red[64][16];
  int b = blockIdx.x; int n = b / 144; int px0 = (b % 144) * 64;
  int t = threadIdx.x; int q = t & 3, pxl = t >> 2;
  for (int e = t; e < 512; e += 256) wsh[e] = w[e];
  if (t < 128) { gsh[t] = gam[t]; bsh[t] = bet[t]; }
  __syncthreads();
  const float invc = 1.f / (64.f * 9216.f);
  int g = q >> 1;
  const float* st = stats3 + (n * 2 + g) * 2;
  float mu = st[0] * invc;
  float var = fmaf(-mu, mu, st[1] * invc);
  float rsv = rsqrtf(var + 1e-5f);
  const float* yb = y + (size_t)(n * 9216 + px0 + pxl) * 128 + q * 32;
  float s0 = 0.f, s1 = 0.f, s2 = 0.f, s3 = 0.f;
#pragma unroll
  for (int j = 0; j < 8; ++j) {
    float4 v = *(const float4*)(yb + j * 4);
    int c0 = q * 32 + j * 4;
    float vx = lrelu_f(fmaf((v.x - mu) * rsv, gsh[c0 + 0], bsh[c0 + 0]));
    float vy = lrelu_f(fmaf((v.y - mu) * rsv, gsh[c0 + 1], bsh[c0 + 1]));
    float vz = lrelu_f(fmaf((v.z - mu) * rsv, gsh[c0 + 2], bsh[c0 + 2]));
    float vw = lrelu_f(fmaf((v.w - mu) * rsv, gsh[c0 + 3], bsh[c0 + 3]));
    const float* w0 = &wsh[0 * 128 + c0];
    const float* w1 = &wsh[1 * 128 + c0];
    const float* w2 = &wsh[2 * 128 + c0];
    const float* w3 = &wsh[3 * 128 + c0];
    s0 += vx * w0[0] + vy * w0[1] + vz * w0[2] + vw * w0[3];
    s1 += vx * w1[0] + vy * w1[1] + vz * w1[2] + vw * w1[3];
    s2 += vx * w2[0] + vy * w2[1] + vz * w2[2] + vw * w2[3];
    s3 += vx * w3[0] + vy * w3[1] + vz * w3[2] + vw * w3[3];
  }
  red[pxl][q * 4 + 0] = s0; red[pxl][q * 4 + 1] = s1;
  red[pxl][q * 4 + 2] = s2; red[pxl][q * 4 + 3] = s3;
  __syncthreads();
  float val = red[pxl][0 * 4 + q] + red[pxl][1 * 4 + q] + red[pxl][2 * 4 + q] + red[pxl][3 * 4 + q] + bias[q];
  out[1 + (size_t)(n * 4 + q) * 9216 + px0 + pxl] = val;
}

extern "C" void kernel_launch(void* const* d_in, const int* in_sizes, int n_in,
                              void* d_out, int out_size, void* d_ws, size_t ws_size,
                              hipStream_t stream) {
  (void)in_sizes; (void)n_in; (void)out_size; (void)ws_size;
  const float* x     = (const float*)d_in[0];
  const float* e0_w  = (const float*)d_in[1];
  const float* e0_b  = (const float*)d_in[2];
  const float* e0_g  = (const float*)d_in[3];
  const float* e0_bt = (const float*)d_in[4];
  const float* e1_w  = (const float*)d_in[5];
  const float* e1_b  = (const float*)d_in[6];
  const float* e1_g  = (const float*)d_in[7];
  const float* e1_bt = (const float*)d_in[8];
  const float* pv_w  = (const float*)d_in[9];
  const float* pv_b  = (const float*)d_in[10];
  const float* emb   = (const float*)d_in[11];
  const float* d0_w  = (const float*)d_in[12];
  const float* d0_b  = (const float*)d_in[13];
  const float* d0_g  = (const float*)d_in[14];
  const float* d0_bt = (const float*)d_in[15];
  const float* d1_w  = (const float*)d_in[16];
  const float* d1_b  = (const float*)d_in[17];
  const float* d1_g  = (const float*)d_in[18];
  const float* d1_bt = (const float*)d_in[19];
  const float* pj_w  = (const float*)d_in[20];
  const float* pj_b  = (const float*)d_in[21];
  const float* ro_w  = (const float*)d_in[22];
  const float* ro_b  = (const float*)d_in[23];
  float* out = (float*)d_out;
  float* ws = (float*)d_ws;

  float* stats  = ws;                       // 64
  float* counts = ws + 64;                  // 1024
  float* enorm  = ws + 1088;                // 1024
  float* pvq    = ws + 2112;                // 1152 (576 used)
  float2* ps_e0 = (float2*)(ws + 3264);
  float2* ps_e1 = (float2*)(ws + 76992);
  float2* ps_d0 = (float2*)(ws + 95424);
  float2* ps_d1 = (float2*)(ws + 107712);
  float* enc1   = ws + 114688;                     // 4,718,592 f (raw e0 out NCHW)
  float* latent = enc1 + (size_t)NB * C * HW;      // 1,179,648 f (raw e1 out NCHW)
  float* zbuf   = latent + (size_t)NB * C * HWL;   // zp bf16 hi/lo [9216][256]
  float* hy     = zbuf + (size_t)NB * C * HWL;     // 4,718,592 f (h,y NHWC)
  u16* qb    = (u16*)(hy + (size_t)NB * C * HW);   // 1,179,648 bf16 NHWC
  u16* hb    = qb + (size_t)NB * C * HWL;          // 4,718,592 bf16 NHWC
  u16* skipb = hb + (size_t)NB * C * HW;           // 4,718,592 bf16 NHWC
  u16* A1    = skipb + (size_t)NB * C * HW;        // 294,912
  u16* A0    = A1 + 294912;                        // 147,456
  u16* Apj   = A0 + 147456;                        // 16,384
  u16* ehtil = Apj + 16384 + 64;                   // tile-major codebook pack, 512 KB
  u16* zp    = (u16*)zbuf;                         // z split pack [9216][zh128|zl128]
  u16* xp  = qb;                                   // 9,535,488 u16 (aliases qb..skipb window)
  u16* We1 = qb + 9535488;                         // 294,912 u16

  k_pack_all<<<2069, 256, 0, stream>>>(d1_w, d0_w, pj_w, emb, e1_w,
                                       A1, A0, Apj, ehtil, We1, enorm, counts);

  k_conv_e0t<<<3072, 256, 0, stream>>>(x, e0_w, e0_b, enc1, ps_e0);
  k_red16<<<8, 256, 0, stream>>>(ps_e0, stats + 0, 384);
  k_gn_px<<<NB * 96 * 4, 256, 0, stream>>>(enc1, stats + 0, e0_g, e0_bt, xp);
  k_conv_e1m<<<NB * 48 * 2, 256, 0, stream>>>(xp, We1, e1_b, latent, ps_e1);
  k_red16<<<8, 256, 0, stream>>>(ps_e1, stats + 16, 48);
  k_pv<<<288, 256, 0, stream>>>(latent, pv_w, pv_b, stats + 16, e1_g, e1_bt, zp);
  k_vq<<<ROWS / 16, 512, 0, stream>>>(zp, ehtil, emb, enorm, qb, counts, pvq);
  k_finalize<<<1, 256, 0, stream>>>(counts, pvq, out);

  k_proj_m<<<NB * 96, 256, 0, stream>>>(enc1, Apj, pj_b, stats + 0, e0_g, e0_bt, skipb);
  k_convt_d0m<<<NB * 96 * 2, 256, 0, stream>>>(qb, A0, d0_b, hy, ps_d0);
  k_red16<<<8, 256, 0, stream>>>(ps_d0, stats + 32, 384);
  k_gn_nhwc_bf<<<NB * C * HW / 256, 256, 0, stream>>>(hy, hb, stats + 32, d0_g, d0_bt);
  k_conv_d1m<<<NB * 96, 256, 0, stream>>>(hb, skipb, A1, d1_b, hy, ps_d1);
  k_red16<<<8, 256, 0, stream>>>(ps_d1, stats + 48, 192);
  k_ro<<<NB * 144, 256, 0, stream>>>(hy, ro_w, ro_b, stats + 48, d1_g, d1_bt, out);
}

// Round 14
// 349.555 us; speedup vs baseline: 1.0192x; 1.0192x over previous
//
#include <hip/hip_runtime.h>

#define DEVI __device__ __forceinline__

typedef unsigned short u16;
typedef __attribute__((ext_vector_type(8))) short bf8v;   // 8 bf16 = 4 VGPR
typedef __attribute__((ext_vector_type(4))) short s4v;    // 4 bf16
typedef __attribute__((ext_vector_type(4))) float f4v;    // MFMA acc

constexpr int NB = 4, C = 128, H = 96, W = 96, HW = H * W;   // 9216
constexpr int HL = 48, WL = 48, HWL = HL * WL;               // 2304
constexpr int CODES = 1024, DIM = 128;
constexpr int ROWS = NB * HWL;                               // 9216 VQ rows

DEVI float lrelu_f(float v) { return v >= 0.f ? v : 0.2f * v; }

DEVI u16 f2bf(float f) {  // RNE float->bf16
  union { float f; unsigned u; } v; v.f = f;
  unsigned r = (v.u + 0x7FFFu + ((v.u >> 16) & 1u)) >> 16;
  return (u16)r;
}

DEVI float bf2f(u16 h) {
  union { unsigned u; float f; } v; v.u = (unsigned)h << 16;
  return v.f;
}

DEVI void wave_red2(float& s, float& s2) {
#pragma unroll
  for (int o = 32; o > 0; o >>= 1) { s += __shfl_down(s, o); s2 += __shfl_down(s2, o); }
}

DEVI bool block_red2(float& s, float& s2) {
  wave_red2(s, s2);
  __shared__ float ls[8], ls2[8];
  int wv = threadIdx.x >> 6, ln = threadIdx.x & 63;
  if (ln == 0) { ls[wv] = s; ls2[wv] = s2; }
  __syncthreads();
  if (threadIdx.x == 0) {
    s = ls[0] + ls[1] + ls[2] + ls[3];
    s2 = ls2[0] + ls2[1] + ls2[2] + ls2[3];
    return true;
  }
  return false;
}

// insert (e,j) into ascending top-3, lexicographic (d, idx)
DEVI void ins3(float e, int j, float& d0, int& i0, float& d1, int& i1, float& d2, int& i2) {
  bool b0 = (e < d0) || (e == d0 && j < i0);
  bool b1 = (e < d1) || (e == d1 && j < i1);
  bool b2 = (e < d2) || (e == d2 && j < i2);
  float nd0 = b0 ? e : d0;             int ni0 = b0 ? j : i0;
  float nd1 = b0 ? d0 : (b1 ? e : d1); int ni1 = b0 ? i0 : (b1 ? j : i1);
  float nd2 = b1 ? d1 : (b2 ? e : d2); int ni2 = b1 ? i1 : (b2 ? j : i2);
  d0 = nd0; i0 = ni0; d1 = nd1; i1 = ni1; d2 = nd2; i2 = ni2;
}

// ---------------- stats reduction: 8 slots, PER partials each ----------------
__global__ __launch_bounds__(256) void k_red16(const float2* __restrict__ src,
                                               float* __restrict__ dst, int per) {
  int slot = blockIdx.x;
  float s = 0.f, s2 = 0.f;
  for (int i = threadIdx.x; i < per; i += 256) {
    float2 v = src[(size_t)slot * per + i];
    s += v.x; s2 += v.y;
  }
  if (block_red2(s, s2)) { dst[slot * 2] = s; dst[slot * 2 + 1] = s2; }
}

// ---------------- unified pre-pack: d1w | d0w | pjw | emb | enorm | counts | e1w(hi/lo slabs) ----------------
// ehtil: per code-tile ct (16 codes), 8 slabs of 1KB; k_vq frag loads = base + lane*16B.
// We1: slab s = ((ky*4+ch)*3+kx)*8+ct; [hi 512 u16][lo 512 u16]; granule l: co=ct*16+(l&15),
//      ci=ch*32+(l>>4)*8..+8  => k_conv_e1m frag loads = slab + lane*8 (+512 for lo).
__global__ __launch_bounds__(256) void k_pack_all(
    const float* __restrict__ d1_w, const float* __restrict__ d0_w,
    const float* __restrict__ pj_w, const float* __restrict__ emb,
    const float* __restrict__ e1_w,
    u16* __restrict__ A1, u16* __restrict__ A0, u16* __restrict__ Apj,
    u16* __restrict__ ehtil, u16* __restrict__ We1,
    float* __restrict__ enorm, float* __restrict__ counts) {
  int b = blockIdx.x, t = threadIdx.x;
  if (b < 1152) {                                  // d1: A1[ky][ch8][kx][co128][ci32]
    int i = b * 256 + t;
    int ci = i & 31, co = (i >> 5) & 127, r = i >> 12;
    int kx = r % 3; int r2 = r / 3; int ch = r2 & 7, ky = r2 >> 3;
    A1[i] = f2bf(d1_w[((size_t)(co * 256 + ch * 32 + ci) * 3 + ky) * 3 + kx]);
  } else if (b < 1728) {                           // d0: A0[wy][ch4][wx][co128][ci32]
    int i = (b - 1152) * 256 + t;
    int ci = i & 31, co = (i >> 5) & 127, r = i >> 12;
    int wx = r % 3; int r2 = r / 3; int ch = r2 & 3, wy = r2 >> 2;
    A0[i] = f2bf(d0_w[((size_t)((ch * 32 + ci) * 128 + co) * 3 + wy) * 3 + wx]);
  } else if (b < 1792) {                           // pj: Apj[ch4][co128][ci32]
    int i = (b - 1728) * 256 + t;
    int ci = i & 31, co = (i >> 5) & 127, ch = i >> 12;
    Apj[i] = f2bf(pj_w[co * 128 + ch * 32 + ci]);
  } else if (b < 1920) {                           // emb tile-major split pack
    int g = (b - 1792) * 256 + t;                  // granule: 8 u16 at ehtil + g*8
    int ct = g >> 9; int rem = g & 511;
    int j = rem >> 6; int l = rem & 63;
    int code = ct * 16 + (l & 15);
    int kb = j * 32 + (l >> 4) * 8;                // u16 index in [eh128|el128] row
    bool lo = kb >= 128; int k0 = lo ? kb - 128 : kb;
    const float* ep = emb + (size_t)code * DIM + k0;
    u16 o[8];
#pragma unroll
    for (int e = 0; e < 8; ++e) {
      float v = ep[e];
      u16 h = f2bf(v);
      o[e] = lo ? f2bf(v - bf2f(h)) : h;
    }
    bf8v ov = {(short)o[0], (short)o[1], (short)o[2], (short)o[3],
               (short)o[4], (short)o[5], (short)o[6], (short)o[7]};
    *(bf8v*)&ehtil[(size_t)g * 8] = ov;
  } else if (b < 1924) {                           // emb row norms (4 blocks)
    int e = (b - 1920) * 256 + t;
    const float4* p = (const float4*)(emb + (size_t)e * DIM);
    float s = 0.f;
#pragma unroll 8
    for (int i = 0; i < 32; ++i) {
      float4 v = p[i];
      s = fmaf(v.x, v.x, s); s = fmaf(v.y, v.y, s); s = fmaf(v.z, v.z, s); s = fmaf(v.w, v.w, s);
    }
    enorm[e] = s;
  } else if (b == 1924) {                          // zero counts (1 block)
#pragma unroll
    for (int k = 0; k < 4; ++k) counts[t + k * 256] = 0.f;
  } else {                                         // e1 weights: 36864 pair-granules
    int p = (b - 1925) * 256 + t;
    int s = p >> 6, l = p & 63;
    int ct = s & 7; int r = s >> 3;
    int kx = r % 3; int r2 = r / 3; int ch = r2 & 3, ky = r2 >> 2;
    int co = ct * 16 + (l & 15), ci0 = ch * 32 + (l >> 4) * 8;
    u16 hh[8], ll[8];
#pragma unroll
    for (int e = 0; e < 8; ++e) {
      float v = e1_w[((size_t)(co * 128 + ci0 + e) * 3 + ky) * 3 + kx];
      u16 h = f2bf(v); hh[e] = h; ll[e] = f2bf(v - bf2f(h));
    }
    bf8v hv = {(short)hh[0], (short)hh[1], (short)hh[2], (short)hh[3],
               (short)hh[4], (short)hh[5], (short)hh[6], (short)hh[7]};
    bf8v lv = {(short)ll[0], (short)ll[1], (short)ll[2], (short)ll[3],
               (short)ll[4], (short)ll[5], (short)ll[6], (short)ll[7]};
    *(bf8v*)&We1[(size_t)s * 1024 + l * 8] = hv;
    *(bf8v*)&We1[(size_t)s * 1024 + 512 + l * 8] = lv;
  }
}

// ---------------- conv e0 tiled: 3x3, Cin=4, s=1, p=1 ----------------
__global__ __launch_bounds__(256) void k_conv_e0t(
    const float* __restrict__ x, const float* __restrict__ wg,
    const float* __restrict__ bias, float* __restrict__ out, float2* __restrict__ ps) {
  __shared__ float xs[4][18][104];
  int b = blockIdx.x;
  int rq = b % 6; int co = (b / 6) & 127; int n = b / 768;
  int t = threadIdx.x;
  int tx = t & 15, r = t >> 4;
  int y0 = rq * 16;
  for (int e = t; e < 4 * 18 * 104; e += 256) {
    int ci = e / 1872; int rem = e - ci * 1872;
    int row = rem / 104; int off = rem - row * 104;
    int iy = y0 - 1 + row; int ix = off - 1;
    float v = 0.f;
    if ((unsigned)iy < 96u && (unsigned)ix < 96u)
      v = x[((size_t)(n * 4 + ci)) * HW + iy * 96 + ix];
    xs[ci][row][off] = v;
  }
  float wr[4][9];
  const float* wp = wg + co * 36;
#pragma unroll
  for (int ci = 0; ci < 4; ++ci)
#pragma unroll
    for (int k = 0; k < 9; ++k) wr[ci][k] = wp[ci * 9 + k];
  float bv = bias[co];
  __syncthreads();
  float acc[6];
#pragma unroll
  for (int p = 0; p < 6; ++p) acc[p] = bv;
#pragma unroll
  for (int ci = 0; ci < 4; ++ci) {
#pragma unroll
    for (int ky = 0; ky < 3; ++ky) {
      const float* rp = &xs[ci][r + ky][6 * tx];
      float f[8];
#pragma unroll
      for (int j = 0; j < 4; ++j) {
        float2 v2 = *(const float2*)(rp + 2 * j);
        f[2 * j] = v2.x; f[2 * j + 1] = v2.y;
      }
      float w0 = wr[ci][ky * 3 + 0], w1 = wr[ci][ky * 3 + 1], w2 = wr[ci][ky * 3 + 2];
#pragma unroll
      for (int p = 0; p < 6; ++p)
        acc[p] = fmaf(w0, f[p], fmaf(w1, f[p + 1], fmaf(w2, f[p + 2], acc[p])));
    }
  }
  float* op = out + ((size_t)(n * 128 + co) * 96 + (y0 + r)) * 96 + 6 * tx;
#pragma unroll
  for (int j = 0; j < 3; ++j) {
    float2 v2 = { acc[2 * j], acc[2 * j + 1] };
    *(float2*)(op + 2 * j) = v2;
  }
  float s = 0.f, s2 = 0.f;
#pragma unroll
  for (int p = 0; p < 6; ++p) { s += acc[p]; s2 += acc[p] * acc[p]; }
  if (block_red2(s, s2)) {
    int slot = n * 2 + (co >> 6);
    ps[(size_t)slot * 384 + (co & 63) * 6 + rq] = make_float2(s, s2);
  }
}

// ---------------- GN(e0)+lrelu -> parity-split hi/lo bf16 pack for e1 MFMA ----------------
// xp[n][iy96][ch4][h2][u97][ci32] u16; u<48: ix=2u (even); u>=48: j=u-48, ix=2j-1 (odd, j=0 border=0)
__global__ __launch_bounds__(256) void k_gn_px(
    const float* __restrict__ enc1, const float* __restrict__ stats,
    const float* __restrict__ gam, const float* __restrict__ bet, u16* __restrict__ xp) {
  int b = blockIdx.x;
  int ch = b & 3; int iy = (b >> 2) % 96; int n = b / 384;
  int t = threadIdx.x;
  const float invc = 1.f / (64.f * 9216.f);
  size_t chunk = ((size_t)((n * 96 + iy) * 4 + ch)) * 6208;
  for (int e = t; e < 388; e += 256) {
    int oct = e / 97, u = e - oct * 97;
    int ix = (u < 48) ? 2 * u : 2 * (u - 48) - 1;
    u16* dh = xp + chunk + u * 32 + oct * 8;
    u16* dl = dh + 3104;
    if (ix < 0) {
      bf8v z = {0, 0, 0, 0, 0, 0, 0, 0};
      *(bf8v*)dh = z; *(bf8v*)dl = z;
      continue;
    }
    u16 hh[8], ll[8];
#pragma unroll
    for (int e8 = 0; e8 < 8; ++e8) {
      int c = ch * 32 + oct * 8 + e8;
      const float* st = stats + (n * 2 + (c >> 6)) * 2;
      float mu = st[0] * invc;
      float var = fmaf(-mu, mu, st[1] * invc);
      float rs = rsqrtf(var + 1e-5f);
      float raw = enc1[((size_t)(n * 128 + c)) * 9216 + iy * 96 + ix];
      float v = lrelu_f(fmaf((raw - mu) * rs, gam[c], bet[c]));
      u16 h = f2bf(v); hh[e8] = h; ll[e8] = f2bf(v - bf2f(h));
    }
    bf8v hv = {(short)hh[0], (short)hh[1], (short)hh[2], (short)hh[3],
               (short)hh[4], (short)hh[5], (short)hh[6], (short)hh[7]};
    bf8v lv = {(short)ll[0], (short)ll[1], (short)ll[2], (short)ll[3],
               (short)ll[4], (short)ll[5], (short)ll[6], (short)ll[7]};
    *(bf8v*)dh = hv; *(bf8v*)dl = lv;
  }
}

// ---------------- e1 conv via split-bf16 MFMA: NO LDS / NO barriers, XCD swizzle ----------------
__global__ __launch_bounds__(256) void k_conv_e1m(
    const u16* __restrict__ xp, const u16* __restrict__ We1,
    const float* __restrict__ bias, float* __restrict__ latent, float2* __restrict__ ps) {
  __shared__ float ls[4], ls2[4];
  int braw = blockIdx.x;
  int b = (braw & 7) * 48 + (braw >> 3);         // 384 = 8 XCD x 48: contiguous work per XCD
  int cb = b & 1; int oy = (b >> 1) % 48; int n = b / 96;
  int t = threadIdx.x; int w = t >> 6; int lane = t & 63;
  int ln16 = lane & 15, quad = lane >> 4;
  int ctg = cb * 4 + w;
  f4v acc[3];
#pragma unroll
  for (int nt = 0; nt < 3; ++nt) acc[nt] = (f4v){0.f, 0.f, 0.f, 0.f};
  for (int ky = 0; ky < 3; ++ky) {
    int iy = 2 * oy + ky - 1;
    if ((unsigned)iy >= 96u) continue;          // zero-pad rows contribute nothing
    for (int ch = 0; ch < 4; ++ch) {
      const u16* chunk = xp + ((size_t)((n * 96 + iy) * 4 + ch)) * 6208;
      const u16* wb = We1 + ((size_t)((ky * 4 + ch) * 3)) * 8192;
      bf8v ah[3], al[3];
#pragma unroll
      for (int kx = 0; kx < 3; ++kx) {
        const u16* sl = wb + (kx * 8 + ctg) * 1024 + lane * 8;
        ah[kx] = *(const bf8v*)sl;
        al[kx] = *(const bf8v*)(sl + 512);
      }
#pragma unroll
      for (int nt = 0; nt < 3; ++nt) {
        int px = nt * 16 + ln16;
        const u16* be = chunk + px * 32 + quad * 8;          // even plane, u=px   (kx=1)
        const u16* bo = chunk + (48 + px) * 32 + quad * 8;   // odd plane,  u=48+px(kx=0), +32 -> (kx=2)
        bf8v bhe  = *(const bf8v*)be;
        bf8v ble  = *(const bf8v*)(be + 3104);
        bf8v bho0 = *(const bf8v*)bo;
        bf8v blo0 = *(const bf8v*)(bo + 3104);
        bf8v bho1 = *(const bf8v*)(bo + 32);
        bf8v blo1 = *(const bf8v*)(bo + 32 + 3104);
        acc[nt] = __builtin_amdgcn_mfma_f32_16x16x32_bf16(ah[1], bhe, acc[nt], 0, 0, 0);
        acc[nt] = __builtin_amdgcn_mfma_f32_16x16x32_bf16(al[1], bhe, acc[nt], 0, 0, 0);
        acc[nt] = __builtin_amdgcn_mfma_f32_16x16x32_bf16(ah[1], ble, acc[nt], 0, 0, 0);
        acc[nt] = __builtin_amdgcn_mfma_f32_16x16x32_bf16(ah[0], bho0, acc[nt], 0, 0, 0);
        acc[nt] = __builtin_amdgcn_mfma_f32_16x16x32_bf16(al[0], bho0, acc[nt], 0, 0, 0);
        acc[nt] = __builtin_amdgcn_mfma_f32_16x16x32_bf16(ah[0], blo0, acc[nt], 0, 0, 0);
        acc[nt] = __builtin_amdgcn_mfma_f32_16x16x32_bf16(ah[2], bho1, acc[nt], 0, 0, 0);
        acc[nt] = __builtin_amdgcn_mfma_f32_16x16x32_bf16(al[2], bho1, acc[nt], 0, 0, 0);
        acc[nt] = __builtin_amdgcn_mfma_f32_16x16x32_bf16(ah[2], blo1, acc[nt], 0, 0, 0);
      }
    }
  }
  int co0 = cb * 64 + w * 16 + quad * 4;
  float4 bv = *(const float4*)&bias[co0];
  float s = 0.f, s2 = 0.f;
#pragma unroll
  for (int nt = 0; nt < 3; ++nt) {
    int px = nt * 16 + ln16;
#pragma unroll
    for (int g = 0; g < 4; ++g) {
      float bvg = (g == 0) ? bv.x : (g == 1) ? bv.y : (g == 2) ? bv.z : bv.w;
      float v = acc[nt][g] + bvg;
      latent[((size_t)(n * 128 + co0 + g)) * 2304 + oy * 48 + px] = v;
      s += v; s2 += v * v;
    }
  }
  wave_red2(s, s2);
  if (lane == 0) { ls[w] = s; ls2[w] = s2; }
  __syncthreads();
  if (t == 0) {
    int slot = n * 2 + cb;
    ps[(size_t)slot * 48 + oy] =
        make_float2(ls[0] + ls[1] + ls[2] + ls[3], ls2[0] + ls2[1] + ls2[2] + ls2[3]);
  }
}

// ---------------- GN + lrelu, NHWC fp32 -> bf16 (d0 layer) ----------------
__global__ __launch_bounds__(256) void k_gn_nhwc_bf(
    const float* __restrict__ in, u16* __restrict__ outb, const float* __restrict__ stats,
    const float* __restrict__ gam, const float* __restrict__ bet) {
  int idx = blockIdx.x * 256 + threadIdx.x;
  int c = idx & 127;
  int n = idx / (9216 * 128);
  const float* st = stats + (n * 2 + (c >> 6)) * 2;
  const float invcnt = 1.f / (64.f * 9216.f);
  float mu = st[0] * invcnt;
  float var = fmaf(-mu, mu, st[1] * invcnt);
  float rs = rsqrtf(var + 1e-5f);
  float v = in[idx];
  outb[idx] = f2bf(lrelu_f(fmaf((v - mu) * rs, gam[c], bet[c])));
}

// ---------------- pv 1x1 conv fp32, fused e1-GN -> zp split bf16 ----------------
__global__ __launch_bounds__(256, 2) void k_pv(
    const float* __restrict__ in, const float* __restrict__ w,
    const float* __restrict__ bias, const float* __restrict__ stats1,
    const float* __restrict__ gam, const float* __restrict__ bet,
    u16* __restrict__ zp) {
  int b = blockIdx.x;
  int pxb = b % 36; int cb = (b / 36) & 1; int n = b / 72;
  int t = threadIdx.x;
  int pxg = t & 7, cg = t >> 3;
  int px0 = pxb * 64 + pxg * 8;
  int cobase = cb * 64 + cg * 2;
  const float invc = 1.f / (64.f * 2304.f);
  float acc[2][8];
#pragma unroll
  for (int c = 0; c < 2; ++c) {
    float bv = bias[cobase + c];
#pragma unroll
    for (int p = 0; p < 8; ++p) acc[c][p] = bv;
  }
  const float* ipb = in + (size_t)n * 128 * HWL + px0;
  for (int ci0 = 0; ci0 < 128; ci0 += 4) {
    float inr[4][8];
#pragma unroll
    for (int i = 0; i < 4; ++i) {
      int c = ci0 + i;
      const float* st = stats1 + (n * 2 + (c >> 6)) * 2;
      float mu = st[0] * invc;
      float var = fmaf(-mu, mu, st[1] * invc);
      float rsv = rsqrtf(var + 1e-5f);
      float ga = gam[c], be = bet[c];
      const float* ip = ipb + (size_t)c * HWL;
      float4 a = *(const float4*)ip; float4 bq = *(const float4*)(ip + 4);
      inr[i][0] = lrelu_f(fmaf((a.x - mu) * rsv, ga, be));
      inr[i][1] = lrelu_f(fmaf((a.y - mu) * rsv, ga, be));
      inr[i][2] = lrelu_f(fmaf((a.z - mu) * rsv, ga, be));
      inr[i][3] = lrelu_f(fmaf((a.w - mu) * rsv, ga, be));
      inr[i][4] = lrelu_f(fmaf((bq.x - mu) * rsv, ga, be));
      inr[i][5] = lrelu_f(fmaf((bq.y - mu) * rsv, ga, be));
      inr[i][6] = lrelu_f(fmaf((bq.z - mu) * rsv, ga, be));
      inr[i][7] = lrelu_f(fmaf((bq.w - mu) * rsv, ga, be));
    }
    float wr[2][4];
#pragma unroll
    for (int c = 0; c < 2; ++c) {
      float4 wv = *(const float4*)&w[(size_t)(cobase + c) * 128 + ci0];
      wr[c][0] = wv.x; wr[c][1] = wv.y; wr[c][2] = wv.z; wr[c][3] = wv.w;
    }
#pragma unroll
    for (int i = 0; i < 4; ++i)
#pragma unroll
      for (int c = 0; c < 2; ++c)
#pragma unroll
        for (int p = 0; p < 8; ++p) acc[c][p] = fmaf(wr[c][i], inr[i][p], acc[c][p]);
  }
#pragma unroll
  for (int p = 0; p < 8; ++p) {
    size_t r = (size_t)n * HWL + px0 + p;
    u16 h0 = f2bf(acc[0][p]); u16 l0 = f2bf(acc[0][p] - bf2f(h0));
    u16 h1 = f2bf(acc[1][p]); u16 l1 = f2bf(acc[1][p] - bf2f(h1));
    unsigned hp = (unsigned)h0 | ((unsigned)h1 << 16);
    unsigned lp = (unsigned)l0 | ((unsigned)l1 << 16);
    *(unsigned*)&zp[r * 256 + cobase] = hp;
    *(unsigned*)&zp[r * 256 + 128 + cobase] = lp;
  }
}

// ---------------- VQ via MFMA: 8-wave blocks, 8 tiles/wave, VGPR<=128 ----------------
__global__ __launch_bounds__(512, 4) void k_vq(
    const u16* __restrict__ zp, const u16* __restrict__ ehtil,
    const float* __restrict__ emb, const float* __restrict__ enorm,
    u16* __restrict__ qb, float* __restrict__ counts, float* __restrict__ pvq) {
  __shared__ float wd[8][16][3];
  __shared__ int   wi[8][16][3];
  __shared__ float lred[8];
  __shared__ int hist[CODES];
  int r0 = blockIdx.x * 16;
  int t = threadIdx.x, w = t >> 6, lane = t & 63;
  int ln16 = lane & 15, quad = lane >> 4;
  hist[t] = 0; hist[t + 512] = 0;
  const u16* zrow = zp + (size_t)(r0 + ln16) * 256 + quad * 8;
  bf8v bh[4], bl[4];
#pragma unroll
  for (int kk = 0; kk < 4; ++kk) {
    bh[kk] = *(const bf8v*)(zrow + kk * 32);
    bl[kk] = *(const bf8v*)(zrow + 128 + kk * 32);
  }
  float d0 = 3.4e38f, d1 = 3.4e38f, d2 = 3.4e38f;
  int i0 = -1, i1 = -1, i2 = -1;
  const u16* abase = ehtil + (size_t)(w * 8) * 4096 + lane * 8;
#pragma unroll
  for (int tt = 0; tt < 8; ++tt) {
    const u16* ap = abase + tt * 4096;
    bf8v af[8];
#pragma unroll
    for (int j = 0; j < 8; ++j) af[j] = *(const bf8v*)(ap + j * 512);   // lane*16B coalesced
    f4v accA = (f4v){0.f, 0.f, 0.f, 0.f};
    f4v accB = (f4v){0.f, 0.f, 0.f, 0.f};
    f4v accC = (f4v){0.f, 0.f, 0.f, 0.f};
#pragma unroll
    for (int kk = 0; kk < 4; ++kk) {   // 3 independent chains; zl*el dropped (~2^-18)
      accA = __builtin_amdgcn_mfma_f32_16x16x32_bf16(af[kk], bh[kk], accA, 0, 0, 0);
      accB = __builtin_amdgcn_mfma_f32_16x16x32_bf16(af[4 + kk], bh[kk], accB, 0, 0, 0);
      accC = __builtin_amdgcn_mfma_f32_16x16x32_bf16(af[kk], bl[kk], accC, 0, 0, 0);
    }
    int cbase = (w * 8 + tt) * 16 + quad * 4;
#pragma unroll
    for (int g = 0; g < 4; ++g) {
      int code = cbase + g;
      float dot = accA[g] + accB[g] + accC[g];
      float d = fmaf(-2.f, dot, enorm[code]);
      // strict < : per-lane candidate codes ascend, ties keep lower idx
      bool b0 = d < d0, b1 = d < d1, b2 = d < d2;
      float nd0 = b0 ? d : d0;             int ni0 = b0 ? code : i0;
      float nd1 = b0 ? d0 : (b1 ? d : d1); int ni1 = b0 ? i0 : (b1 ? code : i1);
      float nd2 = b1 ? d1 : (b2 ? d : d2); int ni2 = b1 ? i1 : (b2 ? code : i2);
      d0 = nd0; i0 = ni0; d1 = nd1; i1 = ni1; d2 = nd2; i2 = ni2;
    }
  }
  // merge across the 4 quads holding the same z-row (xor 16, 32)
#pragma unroll
  for (int off = 16; off <= 32; off <<= 1) {
    float e0 = __shfl_xor(d0, off), e1 = __shfl_xor(d1, off), e2 = __shfl_xor(d2, off);
    int j0 = __shfl_xor(i0, off), j1 = __shfl_xor(i1, off), j2 = __shfl_xor(i2, off);
    ins3(e0, j0, d0, i0, d1, i1, d2, i2);
    ins3(e1, j1, d0, i0, d1, i1, d2, i2);
    ins3(e2, j2, d0, i0, d1, i1, d2, i2);
  }
  if (quad == 0) {
    wd[w][ln16][0] = d0; wd[w][ln16][1] = d1; wd[w][ln16][2] = d2;
    wi[w][ln16][0] = i0; wi[w][ln16][1] = i1; wi[w][ln16][2] = i2;
  }
  __syncthreads();
  // wave w finalizes rows w*2, w*2+1: merge 8 waves' top-3 (24 candidates, disjoint ranges)
  float lsum = 0.f;
  for (int ii = 0; ii < 2; ++ii) {
    int i = w * 2 + ii;
    float bd; int bi;
    if (lane < 24) { bd = wd[lane / 3][i][lane % 3]; bi = wi[lane / 3][i][lane % 3]; }
    else { bd = 3.4e38f; bi = 0x7fffffff; }
    int a[3];
#pragma unroll
    for (int p = 0; p < 3; ++p) {
      float d = bd; int idx = bi;
#pragma unroll
      for (int o = 1; o <= 32; o <<= 1) {
        float od = __shfl_xor(d, o); int oi = __shfl_xor(idx, o);
        if (od < d || (od == d && oi < idx)) { d = od; idx = oi; }
      }
      a[p] = idx;
      if (bi == idx) { bd = 3.4e38f; bi = 0x7fffffff; }   // remove selected candidate
    }
    int r = r0 + i;
    const float* q0p = emb + (size_t)a[0] * DIM;
    const u16* zr = zp + (size_t)r * 256;
    float lp = 0.f;
#pragma unroll
    for (int cc = 0; cc < 2; ++cc) {
      int c = lane + cc * 64;
      float qv = q0p[c];
      qb[(size_t)r * 128 + c] = f2bf(qv);
      float zv = bf2f(zr[c]) + bf2f(zr[128 + c]);
      float dd = zv - qv;
      lp = fmaf(dd, dd, lp);
    }
#pragma unroll
    for (int o = 32; o > 0; o >>= 1) lp += __shfl_down(lp, o);
    if (lane == 0) { lsum += lp; atomicAdd(&hist[a[2]], 1); }
  }
  if (lane == 0) lred[w] = lsum;
  __syncthreads();
  if (t == 0) {
    float s = 0.f;
#pragma unroll
    for (int q = 0; q < 8; ++q) s += lred[q];
    pvq[blockIdx.x] = s;
  }
  // aggregated histogram flush
#pragma unroll
  for (int k = 0; k < 2; ++k) {
    int e = t + k * 512;
    int cnt = hist[e];
    if (cnt) atomicAdd(&counts[e], (float)cnt);
  }
}

// ---------------- finalize ----------------
__global__ __launch_bounds__(256) void k_finalize(
    const float* __restrict__ counts, const float* __restrict__ pvq, float* __restrict__ out) {
  float local = 0.f;
#pragma unroll
  for (int k = 0; k < 4; ++k) {
    float cnt = counts[threadIdx.x + k * 256];
    float pr = cnt * (1.f / (float)ROWS);
    local = fmaf(pr, logf(pr + 1e-10f), local);
  }
  float lsum = 0.f;
  for (int i = threadIdx.x; i < ROWS / 16; i += 256) lsum += pvq[i];
  if (block_red2(local, lsum)) {
    out[1 + NB * 4 * HW] = expf(-local);
    out[0] = 0.25f * lsum * (1.f / (9216.f * 128.f));
  }
}

// ---------------- proj (1x1) MFMA, fused e0-GN on staged enc1 ----------------
__global__ __launch_bounds__(256) void k_proj_m(
    const float* __restrict__ enc1, const u16* __restrict__ Apj,
    const float* __restrict__ bias, const float* __restrict__ stats0,
    const float* __restrict__ gam, const float* __restrict__ bet,
    u16* __restrict__ skipb) {
  __shared__ u16 Ash[128 * 32];
  __shared__ u16 Bsh[96 * 32];
  int b = blockIdx.x; int rowi = b % 96; int n = b / 96; int px0 = rowi * 96;
  int t = threadIdx.x; int w = t >> 6; int lane = t & 63;
  int ln16 = lane & 15, quad = lane >> 4;
  int co0w = (w & 1) * 64; int pxh = (w >> 1) * 48;
  int c_l = t & 31, xg = t >> 5;
  const float invc = 1.f / (64.f * 9216.f);
  f4v acc[4][3];
#pragma unroll
  for (int mt = 0; mt < 4; ++mt)
#pragma unroll
    for (int nt = 0; nt < 3; ++nt) acc[mt][nt] = (f4v){0.f, 0.f, 0.f, 0.f};
  for (int ch = 0; ch < 4; ++ch) {
    __syncthreads();
#pragma unroll
    for (int e = 0; e < 2; ++e) {
      int i = t + e * 256;
      *(bf8v*)&Ash[i * 8] = *(const bf8v*)&Apj[ch * 4096 + i * 8];
    }
    int c = ch * 32 + c_l;
    const float* st = stats0 + (n * 2 + (ch >> 1)) * 2;
    float mu = st[0] * invc;
    float var = fmaf(-mu, mu, st[1] * invc);
    float rsv = rsqrtf(var + 1e-5f);
    float ga = gam[c], be = bet[c];
    const float* ip = enc1 + (size_t)(n * 128 + c) * 9216 + px0 + xg * 12;
#pragma unroll
    for (int j4 = 0; j4 < 3; ++j4) {
      float4 v = *(const float4*)(ip + j4 * 4);
      int pxb = xg * 12 + j4 * 4;
      Bsh[(pxb + 0) * 32 + c_l] = f2bf(lrelu_f(fmaf((v.x - mu) * rsv, ga, be)));
      Bsh[(pxb + 1) * 32 + c_l] = f2bf(lrelu_f(fmaf((v.y - mu) * rsv, ga, be)));
      Bsh[(pxb + 2) * 32 + c_l] = f2bf(lrelu_f(fmaf((v.z - mu) * rsv, ga, be)));
      Bsh[(pxb + 3) * 32 + c_l] = f2bf(lrelu_f(fmaf((v.w - mu) * rsv, ga, be)));
    }
    __syncthreads();
    bf8v af[4];
#pragma unroll
    for (int mt = 0; mt < 4; ++mt)
      af[mt] = *(const bf8v*)&Ash[(co0w + mt * 16 + ln16) * 32 + quad * 8];
#pragma unroll
    for (int nt = 0; nt < 3; ++nt) {
      bf8v bfv = *(const bf8v*)&Bsh[(pxh + nt * 16 + ln16) * 32 + quad * 8];
#pragma unroll
      for (int mt = 0; mt < 4; ++mt)
        acc[mt][nt] = __builtin_amdgcn_mfma_f32_16x16x32_bf16(af[mt], bfv, acc[mt][nt], 0, 0, 0);
    }
  }
#pragma unroll
  for (int mt = 0; mt < 4; ++mt) {
    int co = co0w + mt * 16 + quad * 4;
    float4 bv = *(const float4*)&bias[co];
#pragma unroll
    for (int nt = 0; nt < 3; ++nt) {
      int px = px0 + pxh + nt * 16 + ln16;
      u16* dp = skipb + (size_t)(n * 9216 + px) * 128 + co;
      s4v sv;
      sv.x = (short)f2bf(acc[mt][nt].x + bv.x);
      sv.y = (short)f2bf(acc[mt][nt].y + bv.y);
      sv.z = (short)f2bf(acc[mt][nt].z + bv.z);
      sv.w = (short)f2bf(acc[mt][nt].w + bv.w);
      *(s4v*)dp = sv;
    }
  }
}

// ---------------- d0 conv-transpose MFMA (LDS staged, XCD swizzle) ----------------
__global__ __launch_bounds__(256) void k_convt_d0m(
    const u16* __restrict__ qb, const u16* __restrict__ A0,
    const float* __restrict__ bias, float* __restrict__ h, float2* __restrict__ ps) {
  __shared__ u16 Ash[2 * 128 * 32];
  __shared__ u16 Bsh[49 * 32];
  int braw = blockIdx.x;
  int b = (braw & 7) * 96 + (braw >> 3);         // 768 = 8 XCD x 96, bijective
  int rx = b & 1; int oy = (b >> 1) % 96; int n = b / 192;
  int t = threadIdx.x; int w = t >> 6; int lane = t & 63;
  int ln16 = lane & 15, quad = lane >> 4;
  int co0w = w * 32;
  f4v acc[2][3];
#pragma unroll
  for (int mt = 0; mt < 2; ++mt)
#pragma unroll
    for (int nt = 0; nt < 3; ++nt) acc[mt][nt] = (f4v){0.f, 0.f, 0.f, 0.f};
  int nyt, wys[2], iys[2];
  if (oy & 1) {
    wys[0] = 2; iys[0] = (oy - 1) >> 1;
    wys[1] = 0; iys[1] = (oy + 1) >> 1;
    nyt = (iys[1] < 48) ? 2 : 1;
  } else { wys[0] = 1; iys[0] = oy >> 1; wys[1] = 0; iys[1] = 0; nyt = 1; }
  int nxt = rx ? 2 : 1;
  int wxs[2], xof[2];
  if (rx) { wxs[0] = 2; xof[0] = 0; wxs[1] = 0; xof[1] = 1; }
  else { wxs[0] = 1; xof[0] = 0; wxs[1] = 0; xof[1] = 0; }
  for (int yt = 0; yt < nyt; ++yt) {
    for (int ch = 0; ch < 4; ++ch) {
      __syncthreads();
      for (int e = t; e < nxt * 512; e += 256) {
        int xt = e >> 9, e2 = e & 511;
        const u16* Asrc = A0 + (size_t)(((wys[yt] * 4 + ch) * 3 + wxs[xt]) * 4096);
        *(bf8v*)&Ash[xt * 4096 + e2 * 8] = *(const bf8v*)&Asrc[e2 * 8];
      }
      const u16* bbase = qb + (size_t)(n * 2304 + iys[yt] * 48) * 128 + ch * 32;
      for (int e = t; e < 196; e += 256) {
        int row = e >> 2, seg = e & 3;
        bf8v v = {0, 0, 0, 0, 0, 0, 0, 0};
        if (row < 48) v = *(const bf8v*)&bbase[row * 128 + seg * 8];
        *(bf8v*)&Bsh[row * 32 + seg * 8] = v;
      }
      __syncthreads();
      for (int xt = 0; xt < nxt; ++xt) {
        bf8v af[2];
#pragma unroll
        for (int mt = 0; mt < 2; ++mt)
          af[mt] = *(const bf8v*)&Ash[xt * 4096 + (co0w + mt * 16 + ln16) * 32 + quad * 8];
#pragma unroll
        for (int nt = 0; nt < 3; ++nt) {
          bf8v bfv = *(const bf8v*)&Bsh[(nt * 16 + ln16 + xof[xt]) * 32 + quad * 8];
#pragma unroll
          for (int mt = 0; mt < 2; ++mt)
            acc[mt][nt] = __builtin_amdgcn_mfma_f32_16x16x32_bf16(af[mt], bfv, acc[mt][nt], 0, 0, 0);
        }
      }
    }
  }
  float s = 0.f, s2 = 0.f;
#pragma unroll
  for (int mt = 0; mt < 2; ++mt) {
    int co = co0w + mt * 16 + quad * 4;
    float4 bv = *(const float4*)&bias[co];
#pragma unroll
    for (int nt = 0; nt < 3; ++nt) {
      int px = nt * 16 + ln16;
      int ox = 2 * px + rx;
      float4 v;
      v.x = acc[mt][nt].x + bv.x; v.y = acc[mt][nt].y + bv.y;
      v.z = acc[mt][nt].z + bv.z; v.w = acc[mt][nt].w + bv.w;
      *(float4*)(h + (size_t)(n * 9216 + oy * 96 + ox) * 128 + co) = v;
      s += v.x + v.y + v.z + v.w;
      s2 += v.x * v.x + v.y * v.y + v.z * v.z + v.w * v.w;
    }
  }
  wave_red2(s, s2);
  if (lane == 0) {
    int slot = n * 2 + (w >> 1);
    ps[(size_t)slot * 384 + (oy * 2 + rx) * 2 + (w & 1)] = make_float2(s, s2);
  }
}

// ---------------- d1 conv MFMA (LDS staged, XCD swizzle) ----------------
__global__ __launch_bounds__(256) void k_conv_d1m(
    const u16* __restrict__ hb, const u16* __restrict__ sb,
    const u16* __restrict__ A1, const float* __restrict__ bias,
    float* __restrict__ y, float2* __restrict__ ps) {
  __shared__ u16 Ash[3 * 64 * 32];   // [kx][co64][ci32] 12 KB
  __shared__ u16 Bsh[98 * 32];       // ~6.1 KB
  int braw = blockIdx.x;
  int b = (braw & 7) * 96 + (braw >> 3);         // 768 = 8 XCD x 96, bijective
  int cb = b & 1; int oy = (b >> 1) % 96; int n = b / 192;
  int t = threadIdx.x; int w = t >> 6; int lane = t & 63;
  int ln16 = lane & 15, quad = lane >> 4;
  int co0w = (w & 1) * 32; int pxh = (w >> 1) * 48;
  f4v acc[2][3];
#pragma unroll
  for (int mt = 0; mt < 2; ++mt)
#pragma unroll
    for (int nt = 0; nt < 3; ++nt) acc[mt][nt] = (f4v){0.f, 0.f, 0.f, 0.f};
  int ky0 = (oy == 0) ? 1 : 0, ky1 = (oy == 95) ? 1 : 2;
  for (int ky = ky0; ky <= ky1; ++ky) {
    int iy = oy + ky - 1;
    for (int ch = 0; ch < 8; ++ch) {
      const u16* src = (ch < 4) ? hb : sb;
      int c0 = (ch & 3) * 32;
      const u16* Asrc = A1 + (size_t)(ky * 8 + ch) * 12288;
      const u16* bbase = src + (size_t)(n * 9216 + iy * 96) * 128 + c0;
      __syncthreads();
#pragma unroll
      for (int j = 0; j < 3; ++j) {
        int e = t + j * 256;
        int kx = e >> 8; int e2 = e & 255; int co_l = e2 >> 2; int seg = e2 & 3;
        *(bf8v*)&Ash[(kx * 64 + co_l) * 32 + seg * 8] =
            *(const bf8v*)&Asrc[(size_t)kx * 4096 + (cb * 64 + co_l) * 32 + seg * 8];
      }
      for (int e = t; e < 392; e += 256) {
        int row = e >> 2, seg = e & 3;
        int ix = row - 1;
        bf8v v = {0, 0, 0, 0, 0, 0, 0, 0};
        if ((unsigned)ix < 96u) v = *(const bf8v*)&bbase[ix * 128 + seg * 8];
        *(bf8v*)&Bsh[row * 32 + seg * 8] = v;
      }
      __syncthreads();
#pragma unroll
      for (int kx = 0; kx < 3; ++kx) {
        bf8v af[2];
#pragma unroll
        for (int mt = 0; mt < 2; ++mt)
          af[mt] = *(const bf8v*)&Ash[(kx * 64 + co0w + mt * 16 + ln16) * 32 + quad * 8];
#pragma unroll
        for (int nt = 0; nt < 3; ++nt) {
          bf8v bfv = *(const bf8v*)&Bsh[(pxh + nt * 16 + ln16 + kx) * 32 + quad * 8];
#pragma unroll
          for (int mt = 0; mt < 2; ++mt)
            acc[mt][nt] = __builtin_amdgcn_mfma_f32_16x16x32_bf16(af[mt], bfv, acc[mt][nt], 0, 0, 0);
        }
      }
    }
  }
  float s = 0.f, s2 = 0.f;
#pragma unroll
  for (int mt = 0; mt < 2; ++mt) {
    int co = cb * 64 + co0w + mt * 16 + quad * 4;
    float4 bv = *(const float4*)&bias[co];
#pragma unroll
    for (int nt = 0; nt < 3; ++nt) {
      int px = pxh + nt * 16 + ln16;
      float4 v;
      v.x = acc[mt][nt].x + bv.x; v.y = acc[mt][nt].y + bv.y;
      v.z = acc[mt][nt].z + bv.z; v.w = acc[mt][nt].w + bv.w;
      *(float4*)(y + (size_t)(n * 9216 + oy * 96 + px) * 128 + co) = v;
      s += v.x + v.y + v.z + v.w;
      s2 += v.x * v.x + v.y * v.y + v.z * v.z + v.w * v.w;
    }
  }
  wave_red2(s, s2);
  if (lane == 0) {
    int slot = n * 2 + cb;
    ps[(size_t)slot * 384 + oy * 4 + w] = make_float2(s, s2);
  }
}

// ---------------- readout, fused d1-GN ----------------
__global__ __launch_bounds__(256) void k_ro(
    const float* __restrict__ y, const float* __restrict__ w,
    const float* __restrict__ bias, const float* __restrict__ stats3,
    const float* __restrict__ gam, const float* __restrict__ bet,
    float* __restrict__ out) {
  __shared__ float wsh[512];
  __shared__ float gsh[128], bsh[128];
  __shared__ float red[64][16];
  int b = blockIdx.x; int n = b / 144; int px0 = (b % 144) * 64;
  int t = threadIdx.x; int q = t & 3, pxl = t >> 2;
  for (int e = t; e < 512; e += 256) wsh[e] = w[e];
  if (t < 128) { gsh[t] = gam[t]; bsh[t] = bet[t]; }
  __syncthreads();
  const float invc = 1.f / (64.f * 9216.f);
  int g = q >> 1;
  const float* st = stats3 + (n * 2 + g) * 2;
  float mu = st[0] * invc;
  float var = fmaf(-mu, mu, st[1] * invc);
  float rsv = rsqrtf(var + 1e-5f);
  const float* yb = y + (size_t)(n * 9216 + px0 + pxl) * 128 + q * 32;
  float s0 = 0.f, s1 = 0.f, s2 = 0.f, s3 = 0.f;
#pragma unroll
  for (int j = 0; j < 8; ++j) {
    float4 v = *(const float4*)(yb + j * 4);
    int c0 = q * 32 + j * 4;
    float vx = lrelu_f(fmaf((v.x - mu) * rsv, gsh[c0 + 0], bsh[c0 + 0]));
    float vy = lrelu_f(fmaf((v.y - mu) * rsv, gsh[c0 + 1], bsh[c0 + 1]));
    float vz = lrelu_f(fmaf((v.z - mu) * rsv, gsh[c0 + 2], bsh[c0 + 2]));
    float vw = lrelu_f(fmaf((v.w - mu) * rsv, gsh[c0 + 3], bsh[c0 + 3]));
    const float* w0 = &wsh[0 * 128 + c0];
    const float* w1 = &wsh[1 * 128 + c0];
    const float* w2 = &wsh[2 * 128 + c0];
    const float* w3 = &wsh[3 * 128 + c0];
    s0 += vx * w0[0] + vy * w0[1] + vz * w0[2] + vw * w0[3];
    s1 += vx * w1[0] + vy * w1[1] + vz * w1[2] + vw * w1[3];
    s2 += vx * w2[0] + vy * w2[1] + vz * w2[2] + vw * w2[3];
    s3 += vx * w3[0] + vy * w3[1] + vz * w3[2] + vw * w3[3];
  }
  red[pxl][q * 4 + 0] = s0; red[pxl][q * 4 + 1] = s1;
  red[pxl][q * 4 + 2] = s2; red[pxl][q * 4 + 3] = s3;
  __syncthreads();
  float val = red[pxl][0 * 4 + q] + red[pxl][1 * 4 + q] + red[pxl][2 * 4 + q] + red[pxl][3 * 4 + q] + bias[q];
  out[1 + (size_t)(n * 4 + q) * 9216 + px0 + pxl] = val;
}

extern "C" void kernel_launch(void* const* d_in, const int* in_sizes, int n_in,
                              void* d_out, int out_size, void* d_ws, size_t ws_size,
                              hipStream_t stream) {
  (void)in_sizes; (void)n_in; (void)out_size; (void)ws_size;
  const float* x     = (const float*)d_in[0];
  const float* e0_w  = (const float*)d_in[1];
  const float* e0_b  = (const float*)d_in[2];
  const float* e0_g  = (const float*)d_in[3];
  const float* e0_bt = (const float*)d_in[4];
  const float* e1_w  = (const float*)d_in[5];
  const float* e1_b  = (const float*)d_in[6];
  const float* e1_g  = (const float*)d_in[7];
  const float* e1_bt = (const float*)d_in[8];
  const float* pv_w  = (const float*)d_in[9];
  const float* pv_b  = (const float*)d_in[10];
  const float* emb   = (const float*)d_in[11];
  const float* d0_w  = (const float*)d_in[12];
  const float* d0_b  = (const float*)d_in[13];
  const float* d0_g  = (const float*)d_in[14];
  const float* d0_bt = (const float*)d_in[15];
  const float* d1_w  = (const float*)d_in[16];
  const float* d1_b  = (const float*)d_in[17];
  const float* d1_g  = (const float*)d_in[18];
  const float* d1_bt = (const float*)d_in[19];
  const float* pj_w  = (const float*)d_in[20];
  const float* pj_b  = (const float*)d_in[21];
  const float* ro_w  = (const float*)d_in[22];
  const float* ro_b  = (const float*)d_in[23];
  float* out = (float*)d_out;
  float* ws = (float*)d_ws;

  float* stats  = ws;                       // 64
  float* counts = ws + 64;                  // 1024
  float* enorm  = ws + 1088;                // 1024
  float* pvq    = ws + 2112;                // 1152 (576 used)
  float2* ps_e0 = (float2*)(ws + 3264);
  float2* ps_e1 = (float2*)(ws + 76992);
  float2* ps_d0 = (float2*)(ws + 95424);
  float2* ps_d1 = (float2*)(ws + 107712);
  float* enc1   = ws + 114688;                     // 4,718,592 f (raw e0 out NCHW)
  float* latent = enc1 + (size_t)NB * C * HW;      // 1,179,648 f (raw e1 out NCHW)
  float* zbuf   = latent + (size_t)NB * C * HWL;   // zp bf16 hi/lo [9216][256] (exact fit)
  float* hy     = zbuf + (size_t)NB * C * HWL;     // 4,718,592 f (h,y NHWC)
  u16* qb    = (u16*)(hy + (size_t)NB * C * HW);   // 1,179,648 bf16 NHWC
  u16* hb    = qb + (size_t)NB * C * HWL;          // 4,718,592 bf16 NHWC
  u16* skipb = hb + (size_t)NB * C * HW;           // 4,718,592 bf16 NHWC
  u16* A1    = skipb + (size_t)NB * C * HW;        // 294,912
  u16* A0    = A1 + 294912;                        // 147,456
  u16* Apj   = A0 + 147456;                        // 16,384
  u16* ehtil = Apj + 16384 + 64;                   // tile-major codebook pack, 512 KB
  u16* zp    = (u16*)zbuf;                         // z split pack [9216][zh128|zl128]
  // xp (19.07 MB, parity-split hi/lo e1 input) + We1 (576 KB) alias the qb..skipb window
  // (21.2 MB): written by gn_px/pack before e1m, dead before k_vq writes qb / proj_m writes skipb.
  u16* xp  = qb;                                   // 9,535,488 u16
  u16* We1 = qb + 9535488;                         // 294,912 u16 (16B-aligned offset)

  k_pack_all<<<2069, 256, 0, stream>>>(d1_w, d0_w, pj_w, emb, e1_w,
                                       A1, A0, Apj, ehtil, We1, enorm, counts);

  k_conv_e0t<<<3072, 256, 0, stream>>>(x, e0_w, e0_b, enc1, ps_e0);
  k_red16<<<8, 256, 0, stream>>>(ps_e0, stats + 0, 384);
  k_gn_px<<<NB * 96 * 4, 256, 0, stream>>>(enc1, stats + 0, e0_g, e0_bt, xp);
  k_conv_e1m<<<NB * 48 * 2, 256, 0, stream>>>(xp, We1, e1_b, latent, ps_e1);
  k_red16<<<8, 256, 0, stream>>>(ps_e1, stats + 16, 48);
  k_pv<<<288, 256, 0, stream>>>(latent, pv_w, pv_b, stats + 16, e1_g, e1_bt, zp);
  k_vq<<<ROWS / 16, 512, 0, stream>>>(zp, ehtil, emb, enorm, qb, counts, pvq);
  k_finalize<<<1, 256, 0, stream>>>(counts, pvq, out);

  k_proj_m<<<NB * 96, 256, 0, stream>>>(enc1, Apj, pj_b, stats + 0, e0_g, e0_bt, skipb);
  k_convt_d0m<<<NB * 96 * 2, 256, 0, stream>>>(qb, A0, d0_b, hy, ps_d0);
  k_red16<<<8, 256, 0, stream>>>(ps_d0, stats + 32, 384);
  k_gn_nhwc_bf<<<NB * C * HW / 256, 256, 0, stream>>>(hy, hb, stats + 32, d0_g, d0_bt);
  k_conv_d1m<<<NB * 96 * 2, 256, 0, stream>>>(hb, skipb, A1, d1_b, hy, ps_d1);
  k_red16<<<8, 256, 0, stream>>>(ps_d1, stats + 48, 384);
  k_ro<<<NB * 144, 256, 0, stream>>>(hy, ro_w, ro_b, stats + 48, d1_g, d1_bt, out);
}